// Round 9
// baseline (1233.791 us; speedup 1.0000x reference)
//
#include <hip/hip_runtime.h>
#include <hip/hip_bf16.h>
#include <math.h>

// TransformerXL forward. bf16-MFMA GEMMs (BK=64, swizzled) + swapped-operand
// flash rel-attention, split-K over key-tiles (3 chunks), XCD-exact-fit block
// swizzle (per-bn working set L2-resident; FETCH 8MB proves it). K and V MFMA
// fragments are read DIRECTLY from global (L1/L2-hit, VMEM pipe) instead of
// LDS staging -- removes the 4x cross-wave LDS re-read redundancy that made
// the kernel LDS-pipe-bound. LDS holds only Re + Gbt (33 KB -> 4 blocks/CU).
// No-max softmax => chunk partials (O, li) to disjoint buffers; norm kernel
// sums and emits bf16. PV before B2. Classifier on bf16 MFMA path.
// Layout: [t,b,*] flattened, m = t*B_ + b.

#define T_   2048
#define B_   2
#define DM   512
#define NH   8
#define DH   64
#define DI   2048
#define INCH 2048
#define NCLS 64
#define MT   4096   // T_*B_

typedef __attribute__((ext_vector_type(8))) short short8;
typedef __attribute__((ext_vector_type(4))) float float4v;

#define QSCALE 0.1803368801111204f   // 0.125 * log2(e)

__device__ inline ushort f2bf(float f) {
  uint u = __float_as_uint(f);
  return (ushort)((u + 0x7FFFu + ((u >> 16) & 1u)) >> 16);   // RNE
}
__device__ inline float bf2f(ushort h) { return __uint_as_float(((uint)h) << 16); }
__device__ inline uint pkbf(float a, float b) {
  __hip_bfloat162 h = __float22bfloat162_rn(float2{a, b});
  return *(uint*)&h;
}
__device__ inline void gload16(const void* g, void* lds) {
  __builtin_amdgcn_global_load_lds(
      (const __attribute__((address_space(1))) void*)g,
      (__attribute__((address_space(3))) void*)lds, 16, 0, 0);
}

// ---------------------------------------------------------------- pos emb (bf16 out)
__global__ __launch_bounds__(256) void pos_kernel(ushort* __restrict__ pe) {
  int idx = blockIdx.x * 256 + threadIdx.x;
  if (idx >= T_ * DM) return;
  int t = idx >> 9;
  int i = idx & 511;
  int j = (i < 256) ? i : (i - 256);
  double invf = exp(-(double)(2 * j) * (9.210340371976184 / 512.0));
  double a = (double)(T_ - 1 - t) * invf;
  pe[idx] = f2bf((i < 256) ? (float)sin(a) : (float)cos(a));
}

// ---------------------------------------------------------------- fused fp32->bf16 (6 segments)
__global__ __launch_bounds__(256) void cvt6_kernel(
    const float* s0, ushort* d0, int n0,
    const float* s1, ushort* d1, int n1,
    const float* s2, ushort* d2, int n2,
    const float* s3, ushort* d3, int n3,
    const float* s4, ushort* d4, int n4,
    const float* s5, ushort* d5, int n5)
{
  const float* s; ushort* d; int n;
  switch (blockIdx.y) {
    case 0: s = s0; d = d0; n = n0; break;
    case 1: s = s1; d = d1; n = n1; break;
    case 2: s = s2; d = d2; n = n2; break;
    case 3: s = s3; d = d3; n = n3; break;
    case 4: s = s4; d = d4; n = n4; break;
    default: s = s5; d = d5; n = n5; break;
  }
  int i = blockIdx.x * 256 + threadIdx.x;
  if (i >= n) return;
  float4 v = ((const float4*)s)[i];
  ushort4 w = { f2bf(v.x), f2bf(v.y), f2bf(v.z), f2bf(v.w) };
  ((ushort4*)d)[i] = w;
}

// ---------------------------------------------------------------- clsw f32[64][512] -> bf16[128][512] zero-padded
__global__ __launch_bounds__(256) void clsw_cvt_kernel(const float* __restrict__ w,
                                                       ushort* __restrict__ wb) {
  int i = blockIdx.x * 256 + threadIdx.x;   // 16384 ushort4 groups = 128*512/4
  ushort4 o;
  if (i < 8192) {   // rows 0..63
    float4 v = ((const float4*)w)[i];
    o = ushort4{ f2bf(v.x), f2bf(v.y), f2bf(v.z), f2bf(v.w) };
  } else {
    o = ushort4{ 0, 0, 0, 0 };
  }
  ((ushort4*)wb)[i] = o;
}

// ---------------------------------------------------------------- x[B,C,T] -> xb[(t*2+b), C] bf16
__global__ __launch_bounds__(256) void xpose_kernel(const float* __restrict__ x,
                                                    ushort* __restrict__ xb) {
  __shared__ float s[32][33];
  int t0 = blockIdx.x * 32, k0 = blockIdx.y * 32, b = blockIdx.z;
  int tx = threadIdx.x & 31, ty = threadIdx.x >> 5;
#pragma unroll
  for (int l = 0; l < 4; ++l) {
    int k = k0 + ty + l * 8;
    s[ty + l * 8][tx] = x[((size_t)b * INCH + k) * T_ + t0 + tx];
  }
  __syncthreads();
#pragma unroll
  for (int l = 0; l < 4; ++l) {
    int t = t0 + ty + l * 8;
    xb[((size_t)(t * 2 + b)) * INCH + k0 + tx] = f2bf(s[tx][ty + l * 8]);
  }
}

// ---------------------------------------------------------------- V transpose per layer
// heads V section (t,b,n,d) -> vtg[((b*8+n)*64+d)][t]
__global__ __launch_bounds__(256) void vtrans_kernel(const ushort* __restrict__ heads,
                                                     ushort* __restrict__ vtg) {
  __shared__ ushort s[64][72];
  const int tid = threadIdx.x;
  int t0 = blockIdx.x * 64;
  int b = blockIdx.y & 1, n = blockIdx.y >> 1;
  for (int e = tid; e < 512; e += 256) {
    int r = e >> 3, c = e & 7;
    *(uint4*)&s[r][c * 8] =
        *(const uint4*)&heads[(size_t)((t0 + r) * 2 + b) * 1536 + 1024 + n * 64 + c * 8];
  }
  __syncthreads();
  for (int e = tid; e < 512; e += 256) {
    int d = e >> 3, c = e & 7;
    ushort tmp[8];
#pragma unroll
    for (int j = 0; j < 8; ++j) tmp[j] = s[c * 8 + j][d];
    *(uint4*)&vtg[((size_t)((b * 8 + n) * 64 + d)) * (size_t)T_ + t0 + c * 8] = *(uint4*)tmp;
  }
}

// ---------------------------------------------------------------- bf16 MFMA GEMM (BK=64)
template<int TM, int OUTMODE, bool RELU>
__global__ __launch_bounds__(256) void gemm_bf16(
    const ushort* __restrict__ A, const ushort* __restrict__ W,
    const float* __restrict__ bias, float* __restrict__ Cf, ushort* __restrict__ Cb,
    int M, int N, int K)
{
  __shared__ __attribute__((aligned(16))) ushort As[TM * 64];
  __shared__ __attribute__((aligned(16))) ushort Bs[128 * 64];
  const int NI = TM / 32;
  const int tid  = threadIdx.x;
  const int wave = tid >> 6, lane = tid & 63;
  const int quad = lane >> 4, lidx = lane & 15;
  const int m0 = blockIdx.y * TM, n0 = blockIdx.x * 128;
  const int r8 = lane >> 3;
  const int cs = ((lane & 7) ^ (r8 & 7)) * 8;

  float4v acc[NI * 4];
#pragma unroll
  for (int i = 0; i < NI * 4; ++i) acc[i] = (float4v){0.f, 0.f, 0.f, 0.f};

  const int wm = (wave >> 1) * (TM / 2), wn = (wave & 1) * 64;

  for (int k0 = 0; k0 < K; k0 += 64) {
    __syncthreads();
#pragma unroll
    for (int g = 0; g < TM / 32; ++g) {
      int r0 = wave * 8 + g * 32;
      gload16(A + (size_t)(m0 + r0 + r8) * K + k0 + cs, &As[r0 * 64]);
    }
#pragma unroll
    for (int g = 0; g < 4; ++g) {
      int r0 = wave * 8 + g * 32;
      gload16(W + (size_t)(n0 + r0 + r8) * K + k0 + cs, &Bs[r0 * 64]);
    }
    __syncthreads();

#pragma unroll
    for (int kb = 0; kb < 2; ++kb) {
      short8 af[NI], bf4[4];
      const int ch = (((kb * 4 + quad) ^ (lidx & 7)) * 8);
#pragma unroll
      for (int i = 0; i < NI; ++i)
        af[i] = *(const short8*)&As[(wm + i * 16 + lidx) * 64 + ch];
#pragma unroll
      for (int j = 0; j < 4; ++j)
        bf4[j] = *(const short8*)&Bs[(wn + j * 16 + lidx) * 64 + ch];
#pragma unroll
      for (int i = 0; i < NI; ++i)
#pragma unroll
        for (int j = 0; j < 4; ++j)
          acc[i * 4 + j] = __builtin_amdgcn_mfma_f32_16x16x32_bf16(af[i], bf4[j], acc[i * 4 + j], 0, 0, 0);
    }
  }

  float bj[4];
#pragma unroll
  for (int j = 0; j < 4; ++j) bj[j] = bias ? bias[n0 + wn + j * 16 + lidx] : 0.f;
#pragma unroll
  for (int i = 0; i < NI; ++i) {
    int rbase = m0 + wm + i * 16 + quad * 4;
#pragma unroll
    for (int j = 0; j < 4; ++j) {
      int col = n0 + wn + j * 16 + lidx;
#pragma unroll
      for (int reg = 0; reg < 4; ++reg) {
        float v = acc[i * 4 + j][reg] + bj[j];
        if (RELU) v = fmaxf(v, 0.f);
        size_t off = (size_t)(rbase + reg) * N + col;
        if (OUTMODE != 1) Cf[off] = v;
        if (OUTMODE != 0) Cb[off] = f2bf(v);
      }
    }
  }
}

// ---------------------------------------------------------------- MFMA flash rel-attn (swapped, split-K)
// Grid 1536 blocks; flat id F remapped XCD-exact-fit (XCD = F%8): each XCD's
// blocks share one bn working set -> K/V/rk L2-resident. K/V MFMA fragments
// are loaded per-lane DIRECTLY from global (16B contiguous slices; L1/L2-hit)
// -- no Ks/Vt LDS staging, removing the 4x cross-wave LDS re-read redundancy.
// LDS holds only Re (G operand, global_load_lds-staged) + Gbt. AC swapped:
// S^T = mfma(K, Q), S lane-local per q-row; rel_shift gather from Gbt with
// uniform sel fast paths; no-max base-2 softmax in regs (raw v_exp_f32);
// P packed via v_cvt_pk_bf16_f32 + permlane{32,16}_swap; PV before B2.
// O/li chunk partials go to disjoint per-chunk buffers (plain stores).
#define GT 68

__device__ inline short8 bfrag(const char* base, int lidx, int quad, int kb) {
  return *(const short8*)(base + lidx * 128 + ((((kb << 2) + quad) ^ (lidx & 7)) << 4));
}

__global__ __launch_bounds__(256, 4) void attn_mfma_kernel(
    const ushort* __restrict__ heads, const ushort* __restrict__ rk,
    const ushort* __restrict__ vtg,
    const float* __restrict__ rwb, const float* __restrict__ rrb,
    float* __restrict__ O0, float* __restrict__ O1, float* __restrict__ O2,
    float* __restrict__ Lp)
{
  __shared__ __attribute__((aligned(16))) ushort Re[128 * 64];   // swizzled [w][d]
  __shared__ __attribute__((aligned(16))) ushort Gbt[128 * GT];  // [w][grow]

  const int tid  = threadIdx.x;
  // ---- XCD-exact-fit remap (assumes XCD = flat%8 round-robin dispatch).
  const int F = blockIdx.x + ((blockIdx.y + (blockIdx.z << 4)) << 5);  // x + 32y + 512z
  const int g  = F & 7;
  const int k  = F >> 3;          // 0..191
  const int r  = k / 96;          // round 0/1
  const int kk = k - r * 96;      // 0..95
  const int bnl = r * 8 + g;      // logical bn
  const int i0   = (kk & 31) * 64;
  const int chunk = kk >> 5;      // 0..2
  const int b    = bnl & 1;
  const int n    = bnl >> 1;
  const int jt0 = (chunk == 0) ? 0  : (chunk == 1 ? 11 : 22);
  const int jt1 = (chunk == 0) ? 11 : (chunk == 1 ? 22 : 32);
  const int wave = tid >> 6;
  const int lane = tid & 63;
  const int quad = lane >> 4;
  const int lidx = lane & 15;
  const int r8   = lane >> 3;
  const int cs8  = ((lane & 7) ^ (r8 & 7)) * 8;
  const int bn64 = (b * 8 + n) * 64;
  const int rloc = wave * 16 + lidx;   // this thread's q-row within block

  // per-lane global bases for direct K/V fragment loads
  const ushort* kbase = heads + (size_t)(lidx * 2 + b) * 1536 + 512 + n * 64 + quad * 8;
  const ushort* vbase = vtg + (size_t)(bn64 + lidx) * (size_t)T_ + quad * 8;

  // ---- Q fragments in registers.
  short8 qw[2], qr4[4][2], q4[2];
  {
    auto qfrag = [&](int row, int kb, const float* bias) -> short8 {
      short8 q;
      if (row < T_) q = *(const short8*)&heads[(size_t)(row * 2 + b) * 1536 + n * 64 + kb * 32 + quad * 8];
      else { for (int t = 0; t < 8; ++t) ((ushort*)&q)[t] = 0; }
      short8 o;
#pragma unroll
      for (int t = 0; t < 8; ++t) {
        float f = (bf2f((ushort)((ushort*)&q)[t]) + bias[n * 64 + kb * 32 + quad * 8 + t]) * QSCALE;
        ((ushort*)&o)[t] = f2bf(f);
      }
      return o;
    };
    qw[0] = qfrag(i0 + rloc, 0, rwb);
    qw[1] = qfrag(i0 + rloc, 1, rwb);
#pragma unroll
    for (int rt = 0; rt < 4; ++rt) {
      int row = i0 + rt * 16 + lidx;
      qr4[rt][0] = qfrag(row, 0, rrb); qr4[rt][1] = qfrag(row, 1, rrb);
    }
    int row4 = i0 + 64 + lidx;
    q4[0] = qfrag(row4, 0, rrb); q4[1] = qfrag(row4, 1, rrb);
  }

  // loop-invariant gather bases: per ktile t, addr of Gbt[w(c0)][rloc]
  int a0[4];
#pragma unroll
  for (int t = 0; t < 4; ++t)
    a0[t] = (t * 16 + quad * 4 + 63 - rloc) * GT + rloc;

  float4v oacc[4];
  float4v liacc = (float4v){0.f, 0.f, 0.f, 0.f};
#pragma unroll
  for (int dt = 0; dt < 4; ++dt) oacc[dt] = (float4v){0.f, 0.f, 0.f, 0.f};
  short8 ones8;
#pragma unroll
  for (int t = 0; t < 8; ++t) ((ushort*)&ones8)[t] = 0x3F80;   // bf16 1.0

  auto stageRe = [&](int jt) {
    int qmin = jt * 64 + 1984 - i0;
#pragma unroll
    for (int q4i = 0; q4i < 4; ++q4i) {
      int r0 = 8 * wave + 32 * q4i;
      int qh = qmin + r0 + r8;
      int p  = (qh > T_) ? (qh - T_ - 1) : ((qh == T_) ? 0 : qh);
      gload16(rk + (size_t)p * 2048 + n * 64 + cs8, &Re[r0 * 64]);
    }
  };
  auto fixup = [&](int jt) {   // zero Rext[T] row (after DMA drained)
    int qmin = jt * 64 + 1984 - i0;
    int Tidx = T_ - qmin;
    if (Tidx >= 0 && Tidx < 128) {
      if (tid < 32) ((uint*)Re)[Tidx * 32 + tid] = 0u;
      __syncthreads();   // orders the write before next iter's G reads of Re
    }
  };

  stageRe(jt0);
  __syncthreads();
  fixup(jt0);

  for (int jt = jt0; jt < jt1; ++jt) {
    const int j0   = jt * 64;
    const int qmin = j0 + 1984 - i0;
    const int wth  = T_ - qmin;   // sel = (w > wth)

    // ---- K fragments direct from global (L1/L2-hit; VMEM pipe, not LDS)
    short8 kf[4][2];
#pragma unroll
    for (int t = 0; t < 4; ++t) {
      const ushort* kp = kbase + (size_t)(j0 + t * 16) * 3072;
      kf[t][0] = *(const short8*)(kp);
      kf[t][1] = *(const short8*)(kp + 32);
    }

    // ---- AC swapped: sv[t][reg] = S[key t*16+quad*4+reg][row lidx(=rloc)]
    float4v sv[4];
#pragma unroll
    for (int t = 0; t < 4; ++t) {
      float4v c = {0.f, 0.f, 0.f, 0.f};
      c = __builtin_amdgcn_mfma_f32_16x16x32_bf16(kf[t][0], qw[0], c, 0, 0, 0);
      c = __builtin_amdgcn_mfma_f32_16x16x32_bf16(kf[t][1], qw[1], c, 0, 0, 0);
      sv[t] = c;
    }

    // ---- G: strips {wave, wave+4}; C: col->w, row->grow; aligned uint2 stores
#pragma unroll
    for (int si = 0; si < 2; ++si) {
      const int ws = wave + si * 4;
      const int w0 = ws * 16;
      const char* ReW = (const char*)Re + w0 * 128;
      short8 rb0 = bfrag(ReW, lidx, quad, 0);
      short8 rb1 = bfrag(ReW, lidx, quad, 1);
#pragma unroll
      for (int rt = 0; rt < 4; ++rt) {
        bool need = si == 0 ? (rt >= 3 - wave) : (rt <= 3 - wave);
        if (need) {
          float4v g2 = {0.f, 0.f, 0.f, 0.f};
          g2 = __builtin_amdgcn_mfma_f32_16x16x32_bf16(qr4[rt][0], rb0, g2, 0, 0, 0);
          g2 = __builtin_amdgcn_mfma_f32_16x16x32_bf16(qr4[rt][1], rb1, g2, 0, 0, 0);
          uint2 st; st.x = pkbf(g2[0], g2[1]); st.y = pkbf(g2[2], g2[3]);
          *(uint2*)&Gbt[(w0 + lidx) * GT + rt * 16 + quad * 4] = st;
        }
      }
      if (si == 0 && wth < 63) {   // grow=64 row (for sel at r=63), strips w<64
        float4v g2 = {0.f, 0.f, 0.f, 0.f};
        g2 = __builtin_amdgcn_mfma_f32_16x16x32_bf16(q4[0], rb0, g2, 0, 0, 0);
        g2 = __builtin_amdgcn_mfma_f32_16x16x32_bf16(q4[1], rb1, g2, 0, 0, 0);
        if (quad == 0) Gbt[(w0 + lidx) * GT + 64] = f2bf(g2[0]);
      }
    }
    __syncthreads();   // B1: Gbt ready; Re consumed

    if (jt + 1 < jt1) stageRe(jt + 1);   // DMA overlaps gather+pack+PV; drains at B2

    // ---- gather BD + no-max base-2 softmax, in registers (raw v_exp_f32)
    // sel = (c > cth) is block-uniform-classifiable: no-sel iff wth>=126,
    // all-sel iff wth<0; mixed hits <=2 iterations per block.
    if (wth >= 126) {
#pragma unroll
      for (int t = 0; t < 4; ++t)
#pragma unroll
        for (int r2 = 0; r2 < 4; ++r2)
          sv[t][r2] = __builtin_amdgcn_exp2f(sv[t][r2] + bf2f(Gbt[a0[t] + r2 * GT]));
    } else if (wth < 0) {
#pragma unroll
      for (int t = 0; t < 4; ++t)
#pragma unroll
        for (int r2 = 0; r2 < 4; ++r2)
          sv[t][r2] = __builtin_amdgcn_exp2f(sv[t][r2] + bf2f(Gbt[a0[t] + r2 * GT + 1]));
    } else {
      const int cth = wth + rloc - 63;   // sel = (c > cth)
#pragma unroll
      for (int t = 0; t < 4; ++t) {
        const int c0 = t * 16 + quad * 4;
#pragma unroll
        for (int r2 = 0; r2 < 4; ++r2) {
          int ga = a0[t] + r2 * GT + ((c0 + r2 > cth) ? 1 : 0);
          sv[t][r2] = __builtin_amdgcn_exp2f(sv[t][r2] + bf2f(Gbt[ga]));
        }
      }
    }

    // ---- V fragments direct from global (L1/L2-hit)
    short8 vb[4][2];
#pragma unroll
    for (int dt = 0; dt < 4; ++dt) {
      const ushort* vp = vbase + (size_t)dt * 16 * T_ + j0;
      vb[dt][0] = *(const short8*)(vp);
      vb[dt][1] = *(const short8*)(vp + 32);
    }

    // ---- pack P to bf16 + in-register quad redistribution -> PV A-frags
    // af[kb] elem j = P[row=lidx][key kb*32+quad*8+j]
    short8 af[2];
#pragma unroll
    for (int kb = 0; kb < 2; ++kb) {
      uint mm[4];
#pragma unroll
      for (int i = 0; i < 2; ++i) {
        uint e, o;
        asm("v_cvt_pk_bf16_f32 %0, %1, %2" : "=v"(e) : "v"(sv[2 * kb][2 * i]),     "v"(sv[2 * kb][2 * i + 1]));
        asm("v_cvt_pk_bf16_f32 %0, %1, %2" : "=v"(o) : "v"(sv[2 * kb + 1][2 * i]), "v"(sv[2 * kb + 1][2 * i + 1]));
        asm("v_permlane32_swap_b32 %0, %1" : "+v"(e), "+v"(o));
        asm("v_permlane16_swap_b32 %0, %1" : "+v"(e), "+v"(o));
        mm[i] = e; mm[2 + i] = o;
      }
      union { uint u[4]; short8 s; } cv;
      cv.u[0] = mm[0]; cv.u[1] = mm[1]; cv.u[2] = mm[2]; cv.u[3] = mm[3];
      af[kb] = cv.s;
    }

    // ---- PV + li (pure registers): before B2 to extend Re DMA shadow
#pragma unroll
    for (int dt = 0; dt < 4; ++dt) {
      oacc[dt] = __builtin_amdgcn_mfma_f32_16x16x32_bf16(af[0], vb[dt][0], oacc[dt], 0, 0, 0);
      oacc[dt] = __builtin_amdgcn_mfma_f32_16x16x32_bf16(af[1], vb[dt][1], oacc[dt], 0, 0, 0);
    }
    liacc = __builtin_amdgcn_mfma_f32_16x16x32_bf16(af[0], ones8, liacc, 0, 0, 0);
    liacc = __builtin_amdgcn_mfma_f32_16x16x32_bf16(af[1], ones8, liacc, 0, 0, 0);

    __syncthreads();   // B2: Gbt consumed; Re(jt+1) DMA drained

    if (jt + 1 < jt1) fixup(jt + 1);
  }

  // ---- epilogue: plain stores to this chunk's disjoint partial buffer
  float* __restrict__ Oc = (chunk == 0) ? O0 : (chunk == 1 ? O1 : O2);
  float* __restrict__ Lc = Lp + chunk * (16 * T_);
  const int rowg0 = (b * 8 + n) * T_ + i0 + wave * 16 + quad * 4;
#pragma unroll
  for (int reg = 0; reg < 4; ++reg) {
    int rowg = rowg0 + reg;
#pragma unroll
    for (int dt = 0; dt < 4; ++dt)
      Oc[(size_t)rowg * 64 + dt * 16 + lidx] = oacc[dt][reg];
    if (lidx == 0) Lc[rowg] = liacc[reg];
  }
}

// ---------------------------------------------------------------- sum partials, normalize -> avec bf16
__global__ __launch_bounds__(256) void attn_norm_kernel(
    const float* __restrict__ O0, const float* __restrict__ O1,
    const float* __restrict__ O2, const float* __restrict__ Lp,
    ushort* __restrict__ avec)
{
  int idx = blockIdx.x * 256 + threadIdx.x;   // over [bn][row][d4], 16*2048*16
  int d4  = idx & 15;
  int row = (idx >> 4) & 2047;
  int bn  = idx >> 15;
  float4 v0 = ((const float4*)O0)[idx];
  float4 v1 = ((const float4*)O1)[idx];
  float4 v2 = ((const float4*)O2)[idx];
  int rg = (bn << 11) + row;
  float li = Lp[rg] + Lp[rg + 16 * T_] + Lp[rg + 32 * T_];
  float inv = 1.0f / li;
  int b = bn >> 3, n = bn & 7;
  ushort4 w = { f2bf((v0.x + v1.x + v2.x) * inv), f2bf((v0.y + v1.y + v2.y) * inv),
                f2bf((v0.z + v1.z + v2.z) * inv), f2bf((v0.w + v1.w + v2.w) * inv) };
  *(ushort4*)&avec[(size_t)(row * 2 + b) * DM + n * 64 + d4 * 4] = w;
}

// ---------------------------------------------------------------- LN(residual), dual out
__global__ __launch_bounds__(256) void ln_res_kernel(
    float* __restrict__ h, ushort* __restrict__ hb, const float* __restrict__ delta,
    const float* __restrict__ s, const float* __restrict__ bb)
{
  const int m = blockIdx.x;
  const int tid = threadIdx.x;
  float* hp = h + (size_t)m * DM;
  ushort* hbp = hb + (size_t)m * DM;
  const float* dp = delta + (size_t)m * DM;
  float x0 = hp[tid] + dp[tid];
  float x1 = hp[tid + 256] + dp[tid + 256];
  float sum = x0 + x1, sq = x0 * x0 + x1 * x1;
#pragma unroll
  for (int o = 32; o > 0; o >>= 1) { sum += __shfl_down(sum, o); sq += __shfl_down(sq, o); }
  __shared__ float part[8];
  int wv = tid >> 6;
  if ((tid & 63) == 0) { part[wv * 2] = sum; part[wv * 2 + 1] = sq; }
  __syncthreads();
  float ts = part[0] + part[2] + part[4] + part[6];
  float tq = part[1] + part[3] + part[5] + part[7];
  float mu = ts * (1.f / DM);
  float var = tq * (1.f / DM) - mu * mu;
  float rs = rsqrtf(var + 1e-5f);
  float y0 = (x0 - mu) * rs * s[tid]       + bb[tid];
  float y1 = (x1 - mu) * rs * s[tid + 256] + bb[tid + 256];
  hp[tid] = y0;       hbp[tid] = f2bf(y0);
  hp[tid + 256] = y1; hbp[tid + 256] = f2bf(y1);
}

// ---------------------------------------------------------------- classifier reorder (+bias)
__global__ __launch_bounds__(256) void reorder_kernel(const float* __restrict__ ct,
                                                      const float* __restrict__ cb,
                                                      float* __restrict__ out) {
  int idx = blockIdx.x * 256 + threadIdx.x;
  if (idx >= B_ * NCLS * T_) return;
  int t  = idx & (T_ - 1);
  int nc = (idx >> 11) & 63;
  int bb = idx >> 17;
  out[idx] = ct[(size_t)(t * B_ + bb) * 128 + nc] + cb[nc];
}

// ---------------------------------------------------------------- launch
extern "C" void kernel_launch(void* const* d_in, const int* in_sizes, int n_in,
                              void* d_out, int out_size, void* d_ws, size_t ws_size,
                              hipStream_t stream)
{
  const float* x     = (const float*)d_in[0];
  const float* emb_w = (const float*)d_in[1];
  const float* emb_b = (const float*)d_in[2];
  const float* rwb   = (const float*)d_in[3];
  const float* rrb   = (const float*)d_in[4];
  const float* qkv_w = (const float*)d_in[5];
  const float* qkv_b = (const float*)d_in[6];
  const float* rproj = (const float*)d_in[7];
  const float* o_w   = (const float*)d_in[8];
  const float* ln1s  = (const float*)d_in[9];
  const float* ln1b  = (const float*)d_in[10];
  const float* ff1w  = (const float*)d_in[11];
  const float* ff1b  = (const float*)d_in[12];
  const float* ff2w  = (const float*)d_in[13];
  const float* ff2b  = (const float*)d_in[14];
  const float* ln2s  = (const float*)d_in[15];
  const float* ln2b  = (const float*)d_in[16];
  const float* clsw  = (const float*)d_in[17];
  const float* clsb  = (const float*)d_in[18];
  float* out = (float*)d_out;

  char* p = (char*)d_ws;
  float*  h       = (float*)p;   p += (size_t)MT * DM * 4;
  float*  tmpf    = (float*)p;   p += (size_t)MT * DM * 4;
  ushort* hb      = (ushort*)p;  p += (size_t)MT * DM * 2;
  ushort* headsb  = (ushort*)p;  p += (size_t)MT * 1536 * 2;
  ushort* peb     = (ushort*)p;  p += (size_t)T_ * DM * 2;
  ushort* rk_all  = (ushort*)p;  p += (size_t)T_ * 2048 * 2;
  ushort* avecb   = (ushort*)p;  p += (size_t)MT * DM * 2;
  ushort* xfb     = (ushort*)p;  p += (size_t)MT * INCH * 2;
  ushort* emb_wb  = (ushort*)p;  p += (size_t)DM * INCH * 2;
  ushort* qkv_wb  = (ushort*)p;  p += (size_t)4 * 1536 * DM * 2;
  ushort* rproj_wb= (ushort*)p;  p += (size_t)4 * DM * DM * 2;
  ushort* o_wb    = (ushort*)p;  p += (size_t)4 * DM * DM * 2;
  ushort* ff1_wb  = (ushort*)p;  p += (size_t)4 * DI * DM * 2;
  ushort* ff2_wb  = (ushort*)p;  p += (size_t)4 * DM * DI * 2;
  float*  P2      = (float*)p;   p += (size_t)MT * DM * 4;   // chunk-2 O partial
  float*  Lp      = (float*)p;   p += (size_t)3 * 16 * T_ * 4;
  ushort* cls_wb  = (ushort*)p;  p += (size_t)128 * DM * 2;  // zero-padded bf16 clsw
  ushort* vtg     = xfb;   // region reused; live only vtrans->attn
  // chunk-0 partial = tmpf (free during attn); chunk-1 partial = xfb tail
  // (xfb is 16 MB; vtg uses only the first 4 MB; ff1 rewrites xfb later).
  float*  P0      = tmpf;
  float*  P1      = (float*)(xfb + (size_t)16 * 64 * T_);   // xfb + 4 MB

  cvt6_kernel<<<dim3(4096, 6), 256, 0, stream>>>(
      emb_w, emb_wb, DM * INCH / 4,
      qkv_w, qkv_wb, 4 * 1536 * DM / 4,
      rproj, rproj_wb, 4 * DM * DM / 4,
      o_w,   o_wb,   4 * DM * DM / 4,
      ff1w,  ff1_wb, 4 * DI * DM / 4,
      ff2w,  ff2_wb, 4 * DM * DI / 4);
  clsw_cvt_kernel<<<64, 256, 0, stream>>>(clsw, cls_wb);
  pos_kernel<<<(T_ * DM) / 256, 256, 0, stream>>>(peb);
  xpose_kernel<<<dim3(T_ / 32, INCH / 32, B_), 256, 0, stream>>>(x, xfb);

  gemm_bf16<64, 2, false><<<dim3(DM / 128, MT / 64), 256, 0, stream>>>(
      xfb, emb_wb, emb_b, h, hb, MT, DM, INCH);
  gemm_bf16<128, 1, false><<<dim3(2048 / 128, T_ / 128), 256, 0, stream>>>(
      peb, rproj_wb, nullptr, nullptr, rk_all, T_, 2048, DM);

  for (int l = 0; l < 4; ++l) {
    gemm_bf16<128, 1, false><<<dim3(1536 / 128, MT / 128), 256, 0, stream>>>(
        hb, qkv_wb + (size_t)l * 1536 * DM, qkv_b + l * 1536, nullptr, headsb, MT, 1536, DM);
    vtrans_kernel<<<dim3(T_ / 64, B_ * NH), 256, 0, stream>>>(headsb, vtg);
    attn_mfma_kernel<<<dim3(T_ / 64, B_ * NH, 3), 256, 0, stream>>>(
        headsb, rk_all + (size_t)l * 512, vtg, rwb, rrb, P0, P1, P2, Lp);
    attn_norm_kernel<<<(16 * T_ * 16) / 256, 256, 0, stream>>>(P0, P1, P2, Lp, avecb);
    gemm_bf16<32, 0, false><<<dim3(DM / 128, MT / 32), 256, 0, stream>>>(
        avecb, o_wb + (size_t)l * DM * DM, nullptr, tmpf, nullptr, MT, DM, DM);
    ln_res_kernel<<<MT, 256, 0, stream>>>(h, hb, tmpf, ln1s + l * DM, ln1b + l * DM);
    gemm_bf16<128, 1, true><<<dim3(DI / 128, MT / 128), 256, 0, stream>>>(
        hb, ff1_wb + (size_t)l * DI * DM, ff1b + l * DI, nullptr, xfb, MT, DI, DM);
    gemm_bf16<32, 0, false><<<dim3(DM / 128, MT / 32), 256, 0, stream>>>(
        xfb, ff2_wb + (size_t)l * DM * DI, ff2b + l * DM, tmpf, nullptr, MT, DM, DI);
    ln_res_kernel<<<MT, 256, 0, stream>>>(h, hb, tmpf, ln2s + l * DM, ln2b + l * DM);
  }

  // classifier: bf16 MFMA, N padded to 128 (rows 64.. are zero); bias in reorder
  gemm_bf16<32, 0, false><<<dim3(1, MT / 32), 256, 0, stream>>>(
      hb, cls_wb, nullptr, tmpf, nullptr, MT, 128, DM);
  reorder_kernel<<<(B_ * NCLS * T_) / 256, 256, 0, stream>>>(tmpf, clsb, out);
}

// Round 10
// 826.672 us; speedup vs baseline: 1.4925x; 1.4925x over previous
//
#include <hip/hip_runtime.h>
#include <hip/hip_bf16.h>
#include <math.h>

// TransformerXL forward. bf16-MFMA GEMMs (BK=64, swizzled) + swapped-operand
// flash rel-attention, split-K over key-tiles (3 chunks), XCD-exact-fit block
// swizzle (per-bn working set L2-resident). K/V staged in LDS (coalesced DMA);
// Re staged as a 128-row RING (window slides 64/iter -> only 64 new rows
// DMA'd per iter, -25% staging bytes). No-max softmax => chunk partials to
// disjoint buffers; norm kernel sums and emits bf16. PV before B2.
// Classifier on bf16 MFMA path. Layout: [t,b,*] flattened, m = t*B_ + b.

#define T_   2048
#define B_   2
#define DM   512
#define NH   8
#define DH   64
#define DI   2048
#define INCH 2048
#define NCLS 64
#define MT   4096   // T_*B_

typedef __attribute__((ext_vector_type(8))) short short8;
typedef __attribute__((ext_vector_type(4))) float float4v;

#define QSCALE 0.1803368801111204f   // 0.125 * log2(e)

__device__ inline ushort f2bf(float f) {
  uint u = __float_as_uint(f);
  return (ushort)((u + 0x7FFFu + ((u >> 16) & 1u)) >> 16);   // RNE
}
__device__ inline float bf2f(ushort h) { return __uint_as_float(((uint)h) << 16); }
__device__ inline uint pkbf(float a, float b) {
  __hip_bfloat162 h = __float22bfloat162_rn(float2{a, b});
  return *(uint*)&h;
}
__device__ inline void gload16(const void* g, void* lds) {
  __builtin_amdgcn_global_load_lds(
      (const __attribute__((address_space(1))) void*)g,
      (__attribute__((address_space(3))) void*)lds, 16, 0, 0);
}

// ---------------------------------------------------------------- pos emb (bf16 out)
__global__ __launch_bounds__(256) void pos_kernel(ushort* __restrict__ pe) {
  int idx = blockIdx.x * 256 + threadIdx.x;
  if (idx >= T_ * DM) return;
  int t = idx >> 9;
  int i = idx & 511;
  int j = (i < 256) ? i : (i - 256);
  double invf = exp(-(double)(2 * j) * (9.210340371976184 / 512.0));
  double a = (double)(T_ - 1 - t) * invf;
  pe[idx] = f2bf((i < 256) ? (float)sin(a) : (float)cos(a));
}

// ---------------------------------------------------------------- fused fp32->bf16 (6 segments)
__global__ __launch_bounds__(256) void cvt6_kernel(
    const float* s0, ushort* d0, int n0,
    const float* s1, ushort* d1, int n1,
    const float* s2, ushort* d2, int n2,
    const float* s3, ushort* d3, int n3,
    const float* s4, ushort* d4, int n4,
    const float* s5, ushort* d5, int n5)
{
  const float* s; ushort* d; int n;
  switch (blockIdx.y) {
    case 0: s = s0; d = d0; n = n0; break;
    case 1: s = s1; d = d1; n = n1; break;
    case 2: s = s2; d = d2; n = n2; break;
    case 3: s = s3; d = d3; n = n3; break;
    case 4: s = s4; d = d4; n = n4; break;
    default: s = s5; d = d5; n = n5; break;
  }
  int i = blockIdx.x * 256 + threadIdx.x;
  if (i >= n) return;
  float4 v = ((const float4*)s)[i];
  ushort4 w = { f2bf(v.x), f2bf(v.y), f2bf(v.z), f2bf(v.w) };
  ((ushort4*)d)[i] = w;
}

// ---------------------------------------------------------------- clsw f32[64][512] -> bf16[128][512] zero-padded
__global__ __launch_bounds__(256) void clsw_cvt_kernel(const float* __restrict__ w,
                                                       ushort* __restrict__ wb) {
  int i = blockIdx.x * 256 + threadIdx.x;   // 16384 ushort4 groups = 128*512/4
  ushort4 o;
  if (i < 8192) {   // rows 0..63
    float4 v = ((const float4*)w)[i];
    o = ushort4{ f2bf(v.x), f2bf(v.y), f2bf(v.z), f2bf(v.w) };
  } else {
    o = ushort4{ 0, 0, 0, 0 };
  }
  ((ushort4*)wb)[i] = o;
}

// ---------------------------------------------------------------- x[B,C,T] -> xb[(t*2+b), C] bf16
__global__ __launch_bounds__(256) void xpose_kernel(const float* __restrict__ x,
                                                    ushort* __restrict__ xb) {
  __shared__ float s[32][33];
  int t0 = blockIdx.x * 32, k0 = blockIdx.y * 32, b = blockIdx.z;
  int tx = threadIdx.x & 31, ty = threadIdx.x >> 5;
#pragma unroll
  for (int l = 0; l < 4; ++l) {
    int k = k0 + ty + l * 8;
    s[ty + l * 8][tx] = x[((size_t)b * INCH + k) * T_ + t0 + tx];
  }
  __syncthreads();
#pragma unroll
  for (int l = 0; l < 4; ++l) {
    int t = t0 + ty + l * 8;
    xb[((size_t)(t * 2 + b)) * INCH + k0 + tx] = f2bf(s[tx][ty + l * 8]);
  }
}

// ---------------------------------------------------------------- V transpose per layer
// heads V section (t,b,n,d) -> vtg[((b*8+n)*64+d)][t]
__global__ __launch_bounds__(256) void vtrans_kernel(const ushort* __restrict__ heads,
                                                     ushort* __restrict__ vtg) {
  __shared__ ushort s[64][72];
  const int tid = threadIdx.x;
  int t0 = blockIdx.x * 64;
  int b = blockIdx.y & 1, n = blockIdx.y >> 1;
  for (int e = tid; e < 512; e += 256) {
    int r = e >> 3, c = e & 7;
    *(uint4*)&s[r][c * 8] =
        *(const uint4*)&heads[(size_t)((t0 + r) * 2 + b) * 1536 + 1024 + n * 64 + c * 8];
  }
  __syncthreads();
  for (int e = tid; e < 512; e += 256) {
    int d = e >> 3, c = e & 7;
    ushort tmp[8];
#pragma unroll
    for (int j = 0; j < 8; ++j) tmp[j] = s[c * 8 + j][d];
    *(uint4*)&vtg[((size_t)((b * 8 + n) * 64 + d)) * (size_t)T_ + t0 + c * 8] = *(uint4*)tmp;
  }
}

// ---------------------------------------------------------------- bf16 MFMA GEMM (BK=64)
template<int TM, int OUTMODE, bool RELU>
__global__ __launch_bounds__(256) void gemm_bf16(
    const ushort* __restrict__ A, const ushort* __restrict__ W,
    const float* __restrict__ bias, float* __restrict__ Cf, ushort* __restrict__ Cb,
    int M, int N, int K)
{
  __shared__ __attribute__((aligned(16))) ushort As[TM * 64];
  __shared__ __attribute__((aligned(16))) ushort Bs[128 * 64];
  const int NI = TM / 32;
  const int tid  = threadIdx.x;
  const int wave = tid >> 6, lane = tid & 63;
  const int quad = lane >> 4, lidx = lane & 15;
  const int m0 = blockIdx.y * TM, n0 = blockIdx.x * 128;
  const int r8 = lane >> 3;
  const int cs = ((lane & 7) ^ (r8 & 7)) * 8;

  float4v acc[NI * 4];
#pragma unroll
  for (int i = 0; i < NI * 4; ++i) acc[i] = (float4v){0.f, 0.f, 0.f, 0.f};

  const int wm = (wave >> 1) * (TM / 2), wn = (wave & 1) * 64;

  for (int k0 = 0; k0 < K; k0 += 64) {
    __syncthreads();
#pragma unroll
    for (int g = 0; g < TM / 32; ++g) {
      int r0 = wave * 8 + g * 32;
      gload16(A + (size_t)(m0 + r0 + r8) * K + k0 + cs, &As[r0 * 64]);
    }
#pragma unroll
    for (int g = 0; g < 4; ++g) {
      int r0 = wave * 8 + g * 32;
      gload16(W + (size_t)(n0 + r0 + r8) * K + k0 + cs, &Bs[r0 * 64]);
    }
    __syncthreads();

#pragma unroll
    for (int kb = 0; kb < 2; ++kb) {
      short8 af[NI], bf4[4];
      const int ch = (((kb * 4 + quad) ^ (lidx & 7)) * 8);
#pragma unroll
      for (int i = 0; i < NI; ++i)
        af[i] = *(const short8*)&As[(wm + i * 16 + lidx) * 64 + ch];
#pragma unroll
      for (int j = 0; j < 4; ++j)
        bf4[j] = *(const short8*)&Bs[(wn + j * 16 + lidx) * 64 + ch];
#pragma unroll
      for (int i = 0; i < NI; ++i)
#pragma unroll
        for (int j = 0; j < 4; ++j)
          acc[i * 4 + j] = __builtin_amdgcn_mfma_f32_16x16x32_bf16(af[i], bf4[j], acc[i * 4 + j], 0, 0, 0);
    }
  }

  float bj[4];
#pragma unroll
  for (int j = 0; j < 4; ++j) bj[j] = bias ? bias[n0 + wn + j * 16 + lidx] : 0.f;
#pragma unroll
  for (int i = 0; i < NI; ++i) {
    int rbase = m0 + wm + i * 16 + quad * 4;
#pragma unroll
    for (int j = 0; j < 4; ++j) {
      int col = n0 + wn + j * 16 + lidx;
#pragma unroll
      for (int reg = 0; reg < 4; ++reg) {
        float v = acc[i * 4 + j][reg] + bj[j];
        if (RELU) v = fmaxf(v, 0.f);
        size_t off = (size_t)(rbase + reg) * N + col;
        if (OUTMODE != 1) Cf[off] = v;
        if (OUTMODE != 0) Cb[off] = f2bf(v);
      }
    }
  }
}

// ---------------------------------------------------------------- MFMA flash rel-attn (swapped, split-K)
// Grid 1536 blocks; flat id F remapped XCD-exact-fit (XCD = F%8): each XCD's
// blocks share one bn working set -> K/V/rk L2-resident. Block: 64 q-rows of
// one (b,n); wave owns q-row strip. AC swapped: S^T = mfma(K, Q), S lane-local
// per q-row. Re is a 128-row RING with offset roff in {0,64}: the window
// slides 64 rows/iter, so only 64 new rows are DMA'd per iter (phys =
// (logical + roff) & 127; 16-row strips never straddle the wrap). rel_shift
// gather from Gbt with uniform sel fast paths; no-max base-2 softmax in regs
// (raw v_exp_f32); P packed via v_cvt_pk_bf16_f32 + permlane{32,16}_swap;
// PV before B2. O/li chunk partials to disjoint buffers (plain stores).
#define GT 68

__device__ inline short8 bfrag(const char* base, int lidx, int quad, int kb) {
  return *(const short8*)(base + lidx * 128 + ((((kb << 2) + quad) ^ (lidx & 7)) << 4));
}

__global__ __launch_bounds__(256, 3) void attn_mfma_kernel(
    const ushort* __restrict__ heads, const ushort* __restrict__ rk,
    const ushort* __restrict__ vtg,
    const float* __restrict__ rwb, const float* __restrict__ rrb,
    float* __restrict__ O0, float* __restrict__ O1, float* __restrict__ O2,
    float* __restrict__ Lp)
{
  __shared__ __attribute__((aligned(16))) ushort Ks[64 * 64];    // swizzled [key][d]
  __shared__ __attribute__((aligned(16))) ushort Vt[64 * 64];    // swizzled [d][key]
  __shared__ __attribute__((aligned(16))) ushort Re[128 * 64];   // swizzled [w][d], ring
  __shared__ __attribute__((aligned(16))) ushort Gbt[128 * GT];  // [w][grow]

  const int tid  = threadIdx.x;
  // ---- XCD-exact-fit remap (assumes XCD = flat%8 round-robin dispatch).
  const int F = blockIdx.x + ((blockIdx.y + (blockIdx.z << 4)) << 5);  // x + 32y + 512z
  const int g  = F & 7;
  const int k  = F >> 3;          // 0..191
  const int r  = k / 96;          // round 0/1
  const int kk = k - r * 96;      // 0..95
  const int bnl = r * 8 + g;      // logical bn
  const int i0   = (kk & 31) * 64;
  const int chunk = kk >> 5;      // 0..2
  const int b    = bnl & 1;
  const int n    = bnl >> 1;
  const int jt0 = (chunk == 0) ? 0  : (chunk == 1 ? 11 : 22);
  const int jt1 = (chunk == 0) ? 11 : (chunk == 1 ? 22 : 32);
  const int wave = tid >> 6;
  const int lane = tid & 63;
  const int quad = lane >> 4;
  const int lidx = lane & 15;
  const int r8   = lane >> 3;
  const int cs8  = ((lane & 7) ^ (r8 & 7)) * 8;
  const int bn64 = (b * 8 + n) * 64;
  const int rloc = wave * 16 + lidx;   // this thread's q-row within block

  // ---- Q fragments in registers.
  short8 qw[2], qr4[4][2], q4[2];
  {
    auto qfrag = [&](int row, int kb, const float* bias) -> short8 {
      short8 q;
      if (row < T_) q = *(const short8*)&heads[(size_t)(row * 2 + b) * 1536 + n * 64 + kb * 32 + quad * 8];
      else { for (int t = 0; t < 8; ++t) ((ushort*)&q)[t] = 0; }
      short8 o;
#pragma unroll
      for (int t = 0; t < 8; ++t) {
        float f = (bf2f((ushort)((ushort*)&q)[t]) + bias[n * 64 + kb * 32 + quad * 8 + t]) * QSCALE;
        ((ushort*)&o)[t] = f2bf(f);
      }
      return o;
    };
    qw[0] = qfrag(i0 + rloc, 0, rwb);
    qw[1] = qfrag(i0 + rloc, 1, rwb);
#pragma unroll
    for (int rt = 0; rt < 4; ++rt) {
      int row = i0 + rt * 16 + lidx;
      qr4[rt][0] = qfrag(row, 0, rrb); qr4[rt][1] = qfrag(row, 1, rrb);
    }
    int row4 = i0 + 64 + lidx;
    q4[0] = qfrag(row4, 0, rrb); q4[1] = qfrag(row4, 1, rrb);
  }

  // loop-invariant gather bases: per ktile t, addr of Gbt[w(c0)][rloc]
  int a0[4];
#pragma unroll
  for (int t = 0; t < 4; ++t)
    a0[t] = (t * 16 + quad * 4 + 63 - rloc) * GT + rloc;

  float4v oacc[4];
  float4v liacc = (float4v){0.f, 0.f, 0.f, 0.f};
#pragma unroll
  for (int dt = 0; dt < 4; ++dt) oacc[dt] = (float4v){0.f, 0.f, 0.f, 0.f};
  short8 ones8;
#pragma unroll
  for (int t = 0; t < 8; ++t) ((ushort*)&ones8)[t] = 0x3F80;   // bf16 1.0

  auto stageK = [&](int jt) {
    int j0 = jt * 64;
#pragma unroll
    for (int half = 0; half < 2; ++half) {
      int r0 = 8 * wave + 32 * half;
      gload16(heads + (size_t)((j0 + r0 + r8) * 2 + b) * 1536 + 512 + n * 64 + cs8, &Ks[r0 * 64]);
    }
  };
  auto stageReFull = [&](int jt) {   // all 128 window rows, phys = logical (roff=0)
    int qmin = jt * 64 + 1984 - i0;
#pragma unroll
    for (int q4i = 0; q4i < 4; ++q4i) {
      int r0 = 8 * wave + 32 * q4i;
      int qh = qmin + r0 + r8;
      int p  = (qh > T_) ? (qh - T_ - 1) : ((qh == T_) ? 0 : qh);
      gload16(rk + (size_t)p * 2048 + n * 64 + cs8, &Re[r0 * 64]);
    }
  };
  auto stageReNew = [&](int jt, int roff) {   // 64 new rows for window jt+1
    int qmin = jt * 64 + 1984 - i0;           // w = qmin+128+u -> phys u+roff
#pragma unroll
    for (int half = 0; half < 2; ++half) {
      int u0 = 8 * wave + 32 * half;
      int qh = qmin + 128 + u0 + r8;
      int p  = (qh > T_) ? (qh - T_ - 1) : ((qh == T_) ? 0 : qh);
      gload16(rk + (size_t)p * 2048 + n * 64 + cs8, &Re[(u0 + roff) * 64]);
    }
  };
  auto stageV = [&](int jt) {
    int j0 = jt * 64;
#pragma unroll
    for (int half = 0; half < 2; ++half) {
      int r0 = 8 * wave + 32 * half;
      gload16(vtg + (size_t)(bn64 + r0 + r8) * (size_t)T_ + j0 + cs8, &Vt[r0 * 64]);
    }
  };

  stageK(jt0);
  stageReFull(jt0);
  stageV(jt0);
  __syncthreads();
  {   // initial Rext[T]=0 fixup (full window, phys = logical)
    int Tidx = T_ - (jt0 * 64 + 1984 - i0);
    if (Tidx >= 0 && Tidx < 128) {
      if (tid < 32) ((uint*)Re)[Tidx * 32 + tid] = 0u;
      __syncthreads();
    }
  }

  int roff = 0;   // ring offset, toggles 0<->64 per iteration

  for (int jt = jt0; jt < jt1; ++jt) {
    const int qmin = jt * 64 + 1984 - i0;
    const int wth  = T_ - qmin;   // sel = (w > wth)

    // ---- AC swapped: sv[t][reg] = S[key t*16+quad*4+reg][row lidx(=rloc)]
    float4v sv[4];
#pragma unroll
    for (int t = 0; t < 4; ++t) {
      const char* KsT = (const char*)Ks + t * 2048;
      short8 kf0 = bfrag(KsT, lidx, quad, 0);
      short8 kf1 = bfrag(KsT, lidx, quad, 1);
      float4v c = {0.f, 0.f, 0.f, 0.f};
      c = __builtin_amdgcn_mfma_f32_16x16x32_bf16(kf0, qw[0], c, 0, 0, 0);
      c = __builtin_amdgcn_mfma_f32_16x16x32_bf16(kf1, qw[1], c, 0, 0, 0);
      sv[t] = c;
    }

    // ---- G: strips {wave, wave+4}; C: col->w, row->grow; aligned uint2 stores
#pragma unroll
    for (int si = 0; si < 2; ++si) {
      const int ws = wave + si * 4;
      const int w0 = ws * 16;
      const char* ReW = (const char*)Re + (size_t)(((w0 + roff) & 127) * 128);
      short8 rb0 = bfrag(ReW, lidx, quad, 0);
      short8 rb1 = bfrag(ReW, lidx, quad, 1);
#pragma unroll
      for (int rt = 0; rt < 4; ++rt) {
        bool need = si == 0 ? (rt >= 3 - wave) : (rt <= 3 - wave);
        if (need) {
          float4v g2 = {0.f, 0.f, 0.f, 0.f};
          g2 = __builtin_amdgcn_mfma_f32_16x16x32_bf16(qr4[rt][0], rb0, g2, 0, 0, 0);
          g2 = __builtin_amdgcn_mfma_f32_16x16x32_bf16(qr4[rt][1], rb1, g2, 0, 0, 0);
          uint2 st; st.x = pkbf(g2[0], g2[1]); st.y = pkbf(g2[2], g2[3]);
          *(uint2*)&Gbt[(w0 + lidx) * GT + rt * 16 + quad * 4] = st;
        }
      }
      if (si == 0 && wth < 63) {   // grow=64 row (for sel at r=63), strips w<64
        float4v g2 = {0.f, 0.f, 0.f, 0.f};
        g2 = __builtin_amdgcn_mfma_f32_16x16x32_bf16(q4[0], rb0, g2, 0, 0, 0);
        g2 = __builtin_amdgcn_mfma_f32_16x16x32_bf16(q4[1], rb1, g2, 0, 0, 0);
        if (quad == 0) Gbt[(w0 + lidx) * GT + 64] = f2bf(g2[0]);
      }
    }
    __syncthreads();   // B1: Gbt ready; Ks/Re consumed; Vt(jt) DMA drained

    if (jt + 1 < jt1) {
      stageK(jt + 1);            // DMA overlaps gather+pack+PV; drains at B2
      stageReNew(jt, roff);      // 64 new ring rows into freed half
    }

    // ---- gather BD + no-max base-2 softmax, in registers (raw v_exp_f32)
    // sel = (c > cth) is block-uniform-classifiable: no-sel iff wth>=126,
    // all-sel iff wth<0; mixed hits <=2 iterations per block.
    if (wth >= 126) {
#pragma unroll
      for (int t = 0; t < 4; ++t)
#pragma unroll
        for (int r2 = 0; r2 < 4; ++r2)
          sv[t][r2] = __builtin_amdgcn_exp2f(sv[t][r2] + bf2f(Gbt[a0[t] + r2 * GT]));
    } else if (wth < 0) {
#pragma unroll
      for (int t = 0; t < 4; ++t)
#pragma unroll
        for (int r2 = 0; r2 < 4; ++r2)
          sv[t][r2] = __builtin_amdgcn_exp2f(sv[t][r2] + bf2f(Gbt[a0[t] + r2 * GT + 1]));
    } else {
      const int cth = wth + rloc - 63;   // sel = (c > cth)
#pragma unroll
      for (int t = 0; t < 4; ++t) {
        const int c0 = t * 16 + quad * 4;
#pragma unroll
        for (int r2 = 0; r2 < 4; ++r2) {
          int ga = a0[t] + r2 * GT + ((c0 + r2 > cth) ? 1 : 0);
          sv[t][r2] = __builtin_amdgcn_exp2f(sv[t][r2] + bf2f(Gbt[ga]));
        }
      }
    }

    // ---- V fragments (B-operand: V[key][d], d = dt*16+lidx)
    short8 vb[4][2];
#pragma unroll
    for (int dt = 0; dt < 4; ++dt) {
      const char* VtT = (const char*)Vt + dt * 2048;
      vb[dt][0] = bfrag(VtT, lidx, quad, 0);
      vb[dt][1] = bfrag(VtT, lidx, quad, 1);
    }

    // ---- pack P to bf16 + in-register quad redistribution -> PV A-frags
    // af[kb] elem j = P[row=lidx][key kb*32+quad*8+j]
    short8 af[2];
#pragma unroll
    for (int kb = 0; kb < 2; ++kb) {
      uint mm[4];
#pragma unroll
      for (int i = 0; i < 2; ++i) {
        uint e, o;
        asm("v_cvt_pk_bf16_f32 %0, %1, %2" : "=v"(e) : "v"(sv[2 * kb][2 * i]),     "v"(sv[2 * kb][2 * i + 1]));
        asm("v_cvt_pk_bf16_f32 %0, %1, %2" : "=v"(o) : "v"(sv[2 * kb + 1][2 * i]), "v"(sv[2 * kb + 1][2 * i + 1]));
        asm("v_permlane32_swap_b32 %0, %1" : "+v"(e), "+v"(o));
        asm("v_permlane16_swap_b32 %0, %1" : "+v"(e), "+v"(o));
        mm[i] = e; mm[2 + i] = o;
      }
      union { uint u[4]; short8 s; } cv;
      cv.u[0] = mm[0]; cv.u[1] = mm[1]; cv.u[2] = mm[2]; cv.u[3] = mm[3];
      af[kb] = cv.s;
    }

    // ---- PV + li (pure registers, no LDS): before B2 to extend DMA shadow
#pragma unroll
    for (int dt = 0; dt < 4; ++dt) {
      oacc[dt] = __builtin_amdgcn_mfma_f32_16x16x32_bf16(af[0], vb[dt][0], oacc[dt], 0, 0, 0);
      oacc[dt] = __builtin_amdgcn_mfma_f32_16x16x32_bf16(af[1], vb[dt][1], oacc[dt], 0, 0, 0);
    }
    liacc = __builtin_amdgcn_mfma_f32_16x16x32_bf16(af[0], ones8, liacc, 0, 0, 0);
    liacc = __builtin_amdgcn_mfma_f32_16x16x32_bf16(af[1], ones8, liacc, 0, 0, 0);

    __syncthreads();   // B2: Gbt/Vt consumed; K/ReNew(jt+1) DMA drained

    if (jt + 1 < jt1) {
      stageV(jt + 1);   // DMA overlaps next AC/G; drains at next B1
      roff ^= 64;       // ring advances: next window's logical 0 at new offset
      {   // Rext[T]=0 fixup, only if T is among the newly staged 64 rows
        int Tn = T_ - ((jt + 1) * 64 + 1984 - i0);
        if (Tn >= 64 && Tn < 128) {
          int phys = (Tn + roff) & 127;
          if (tid < 32) ((uint*)Re)[phys * 32 + tid] = 0u;
          __syncthreads();   // orders the write before next iter's G reads
        }
      }
    }
  }

  // ---- epilogue: plain stores to this chunk's disjoint partial buffer
  float* __restrict__ Oc = (chunk == 0) ? O0 : (chunk == 1 ? O1 : O2);
  float* __restrict__ Lc = Lp + chunk * (16 * T_);
  const int rowg0 = (b * 8 + n) * T_ + i0 + wave * 16 + quad * 4;
#pragma unroll
  for (int reg = 0; reg < 4; ++reg) {
    int rowg = rowg0 + reg;
#pragma unroll
    for (int dt = 0; dt < 4; ++dt)
      Oc[(size_t)rowg * 64 + dt * 16 + lidx] = oacc[dt][reg];
    if (lidx == 0) Lc[rowg] = liacc[reg];
  }
}

// ---------------------------------------------------------------- sum partials, normalize -> avec bf16
__global__ __launch_bounds__(256) void attn_norm_kernel(
    const float* __restrict__ O0, const float* __restrict__ O1,
    const float* __restrict__ O2, const float* __restrict__ Lp,
    ushort* __restrict__ avec)
{
  int idx = blockIdx.x * 256 + threadIdx.x;   // over [bn][row][d4], 16*2048*16
  int d4  = idx & 15;
  int row = (idx >> 4) & 2047;
  int bn  = idx >> 15;
  float4 v0 = ((const float4*)O0)[idx];
  float4 v1 = ((const float4*)O1)[idx];
  float4 v2 = ((const float4*)O2)[idx];
  int rg = (bn << 11) + row;
  float li = Lp[rg] + Lp[rg + 16 * T_] + Lp[rg + 32 * T_];
  float inv = 1.0f / li;
  int b = bn >> 3, n = bn & 7;
  ushort4 w = { f2bf((v0.x + v1.x + v2.x) * inv), f2bf((v0.y + v1.y + v2.y) * inv),
                f2bf((v0.z + v1.z + v2.z) * inv), f2bf((v0.w + v1.w + v2.w) * inv) };
  *(ushort4*)&avec[(size_t)(row * 2 + b) * DM + n * 64 + d4 * 4] = w;
}

// ---------------------------------------------------------------- LN(residual), dual out
__global__ __launch_bounds__(256) void ln_res_kernel(
    float* __restrict__ h, ushort* __restrict__ hb, const float* __restrict__ delta,
    const float* __restrict__ s, const float* __restrict__ bb)
{
  const int m = blockIdx.x;
  const int tid = threadIdx.x;
  float* hp = h + (size_t)m * DM;
  ushort* hbp = hb + (size_t)m * DM;
  const float* dp = delta + (size_t)m * DM;
  float x0 = hp[tid] + dp[tid];
  float x1 = hp[tid + 256] + dp[tid + 256];
  float sum = x0 + x1, sq = x0 * x0 + x1 * x1;
#pragma unroll
  for (int o = 32; o > 0; o >>= 1) { sum += __shfl_down(sum, o); sq += __shfl_down(sq, o); }
  __shared__ float part[8];
  int wv = tid >> 6;
  if ((tid & 63) == 0) { part[wv * 2] = sum; part[wv * 2 + 1] = sq; }
  __syncthreads();
  float ts = part[0] + part[2] + part[4] + part[6];
  float tq = part[1] + part[3] + part[5] + part[7];
  float mu = ts * (1.f / DM);
  float var = tq * (1.f / DM) - mu * mu;
  float rs = rsqrtf(var + 1e-5f);
  float y0 = (x0 - mu) * rs * s[tid]       + bb[tid];
  float y1 = (x1 - mu) * rs * s[tid + 256] + bb[tid + 256];
  hp[tid] = y0;       hbp[tid] = f2bf(y0);
  hp[tid + 256] = y1; hbp[tid + 256] = f2bf(y1);
}

// ---------------------------------------------------------------- classifier reorder (+bias)
__global__ __launch_bounds__(256) void reorder_kernel(const float* __restrict__ ct,
                                                      const float* __restrict__ cb,
                                                      float* __restrict__ out) {
  int idx = blockIdx.x * 256 + threadIdx.x;
  if (idx >= B_ * NCLS * T_) return;
  int t  = idx & (T_ - 1);
  int nc = (idx >> 11) & 63;
  int bb = idx >> 17;
  out[idx] = ct[(size_t)(t * B_ + bb) * 128 + nc] + cb[nc];
}

// ---------------------------------------------------------------- launch
extern "C" void kernel_launch(void* const* d_in, const int* in_sizes, int n_in,
                              void* d_out, int out_size, void* d_ws, size_t ws_size,
                              hipStream_t stream)
{
  const float* x     = (const float*)d_in[0];
  const float* emb_w = (const float*)d_in[1];
  const float* emb_b = (const float*)d_in[2];
  const float* rwb   = (const float*)d_in[3];
  const float* rrb   = (const float*)d_in[4];
  const float* qkv_w = (const float*)d_in[5];
  const float* qkv_b = (const float*)d_in[6];
  const float* rproj = (const float*)d_in[7];
  const float* o_w   = (const float*)d_in[8];
  const float* ln1s  = (const float*)d_in[9];
  const float* ln1b  = (const float*)d_in[10];
  const float* ff1w  = (const float*)d_in[11];
  const float* ff1b  = (const float*)d_in[12];
  const float* ff2w  = (const float*)d_in[13];
  const float* ff2b  = (const float*)d_in[14];
  const float* ln2s  = (const float*)d_in[15];
  const float* ln2b  = (const float*)d_in[16];
  const float* clsw  = (const float*)d_in[17];
  const float* clsb  = (const float*)d_in[18];
  float* out = (float*)d_out;

  char* p = (char*)d_ws;
  float*  h       = (float*)p;   p += (size_t)MT * DM * 4;
  float*  tmpf    = (float*)p;   p += (size_t)MT * DM * 4;
  ushort* hb      = (ushort*)p;  p += (size_t)MT * DM * 2;
  ushort* headsb  = (ushort*)p;  p += (size_t)MT * 1536 * 2;
  ushort* peb     = (ushort*)p;  p += (size_t)T_ * DM * 2;
  ushort* rk_all  = (ushort*)p;  p += (size_t)T_ * 2048 * 2;
  ushort* avecb   = (ushort*)p;  p += (size_t)MT * DM * 2;
  ushort* xfb     = (ushort*)p;  p += (size_t)MT * INCH * 2;
  ushort* emb_wb  = (ushort*)p;  p += (size_t)DM * INCH * 2;
  ushort* qkv_wb  = (ushort*)p;  p += (size_t)4 * 1536 * DM * 2;
  ushort* rproj_wb= (ushort*)p;  p += (size_t)4 * DM * DM * 2;
  ushort* o_wb    = (ushort*)p;  p += (size_t)4 * DM * DM * 2;
  ushort* ff1_wb  = (ushort*)p;  p += (size_t)4 * DI * DM * 2;
  ushort* ff2_wb  = (ushort*)p;  p += (size_t)4 * DM * DI * 2;
  float*  P2      = (float*)p;   p += (size_t)MT * DM * 4;   // chunk-2 O partial
  float*  Lp      = (float*)p;   p += (size_t)3 * 16 * T_ * 4;
  ushort* cls_wb  = (ushort*)p;  p += (size_t)128 * DM * 2;  // zero-padded bf16 clsw
  ushort* vtg     = xfb;   // region reused; live only vtrans->attn
  // chunk-0 partial = tmpf (free during attn); chunk-1 partial = xfb tail
  // (xfb is 16 MB; vtg uses only the first 4 MB; ff1 rewrites xfb later).
  float*  P0      = tmpf;
  float*  P1      = (float*)(xfb + (size_t)16 * 64 * T_);   // xfb + 4 MB

  cvt6_kernel<<<dim3(4096, 6), 256, 0, stream>>>(
      emb_w, emb_wb, DM * INCH / 4,
      qkv_w, qkv_wb, 4 * 1536 * DM / 4,
      rproj, rproj_wb, 4 * DM * DM / 4,
      o_w,   o_wb,   4 * DM * DM / 4,
      ff1w,  ff1_wb, 4 * DI * DM / 4,
      ff2w,  ff2_wb, 4 * DM * DI / 4);
  clsw_cvt_kernel<<<64, 256, 0, stream>>>(clsw, cls_wb);
  pos_kernel<<<(T_ * DM) / 256, 256, 0, stream>>>(peb);
  xpose_kernel<<<dim3(T_ / 32, INCH / 32, B_), 256, 0, stream>>>(x, xfb);

  gemm_bf16<64, 2, false><<<dim3(DM / 128, MT / 64), 256, 0, stream>>>(
      xfb, emb_wb, emb_b, h, hb, MT, DM, INCH);
  gemm_bf16<128, 1, false><<<dim3(2048 / 128, T_ / 128), 256, 0, stream>>>(
      peb, rproj_wb, nullptr, nullptr, rk_all, T_, 2048, DM);

  for (int l = 0; l < 4; ++l) {
    gemm_bf16<128, 1, false><<<dim3(1536 / 128, MT / 128), 256, 0, stream>>>(
        hb, qkv_wb + (size_t)l * 1536 * DM, qkv_b + l * 1536, nullptr, headsb, MT, 1536, DM);
    vtrans_kernel<<<dim3(T_ / 64, B_ * NH), 256, 0, stream>>>(headsb, vtg);
    attn_mfma_kernel<<<dim3(T_ / 64, B_ * NH, 3), 256, 0, stream>>>(
        headsb, rk_all + (size_t)l * 512, vtg, rwb, rrb, P0, P1, P2, Lp);
    attn_norm_kernel<<<(16 * T_ * 16) / 256, 256, 0, stream>>>(P0, P1, P2, Lp, avecb);
    gemm_bf16<32, 0, false><<<dim3(DM / 128, MT / 32), 256, 0, stream>>>(
        avecb, o_wb + (size_t)l * DM * DM, nullptr, tmpf, nullptr, MT, DM, DM);
    ln_res_kernel<<<MT, 256, 0, stream>>>(h, hb, tmpf, ln1s + l * DM, ln1b + l * DM);
    gemm_bf16<128, 1, true><<<dim3(DI / 128, MT / 128), 256, 0, stream>>>(
        hb, ff1_wb + (size_t)l * DI * DM, ff1b + l * DI, nullptr, xfb, MT, DI, DM);
    gemm_bf16<32, 0, false><<<dim3(DM / 128, MT / 32), 256, 0, stream>>>(
        xfb, ff2_wb + (size_t)l * DM * DI, ff2b + l * DM, tmpf, nullptr, MT, DM, DI);
    ln_res_kernel<<<MT, 256, 0, stream>>>(h, hb, tmpf, ln2s + l * DM, ln2b + l * DM);
  }

  // classifier: bf16 MFMA, N padded to 128 (rows 64.. are zero); bias in reorder
  gemm_bf16<32, 0, false><<<dim3(1, MT / 32), 256, 0, stream>>>(
      hb, cls_wb, nullptr, tmpf, nullptr, MT, 128, DM);
  reorder_kernel<<<(B_ * NCLS * T_) / 256, 256, 0, stream>>>(tmpf, clsb, out);
}

// Round 11
// 809.197 us; speedup vs baseline: 1.5247x; 1.0216x over previous
//
#include <hip/hip_runtime.h>
#include <hip/hip_bf16.h>
#include <math.h>

// TransformerXL forward. bf16-MFMA GEMMs (BK=64, swizzled) + swapped-operand
// flash rel-attention, split-K over key-tiles (3 chunks), XCD-exact-fit block
// swizzle (per-bn working set L2-resident). Re staged as a 128-row RING.
// V-transpose FUSED into the qkv GEMM epilogue (OUTMODE=3: V col-blocks write
// vtg[(b,n,d)][t] via an LDS transpose of the C-tile; headsb V section never
// written). pos_kernel in f32 (matches the f32 reference; no f64 emulation).
// No-max softmax => chunk partials to disjoint buffers; norm kernel sums and
// emits bf16. PV before B2. Classifier on bf16 MFMA path.
// Layout: [t,b,*] flattened, m = t*B_ + b.

#define T_   2048
#define B_   2
#define DM   512
#define NH   8
#define DH   64
#define DI   2048
#define INCH 2048
#define NCLS 64
#define MT   4096   // T_*B_

typedef __attribute__((ext_vector_type(8))) short short8;
typedef __attribute__((ext_vector_type(4))) float float4v;

#define QSCALE 0.1803368801111204f   // 0.125 * log2(e)

__device__ inline ushort f2bf(float f) {
  uint u = __float_as_uint(f);
  return (ushort)((u + 0x7FFFu + ((u >> 16) & 1u)) >> 16);   // RNE
}
__device__ inline float bf2f(ushort h) { return __uint_as_float(((uint)h) << 16); }
__device__ inline uint pkbf(float a, float b) {
  __hip_bfloat162 h = __float22bfloat162_rn(float2{a, b});
  return *(uint*)&h;
}
__device__ inline void gload16(const void* g, void* lds) {
  __builtin_amdgcn_global_load_lds(
      (const __attribute__((address_space(1))) void*)g,
      (__attribute__((address_space(3))) void*)lds, 16, 0, 0);
}

// ---------------------------------------------------------------- pos emb (bf16 out, f32 math)
__global__ __launch_bounds__(256) void pos_kernel(ushort* __restrict__ pe) {
  int idx = blockIdx.x * 256 + threadIdx.x;
  if (idx >= T_ * DM) return;
  int t = idx >> 9;
  int i = idx & 511;
  int j = (i < 256) ? i : (i - 256);
  // invf = 10000^(-2j/512) = 2^(-2j * log2(1e4)/512)
  float invf = __builtin_amdgcn_exp2f((float)(-2 * j) * 0.025952563241307517f);
  float a = (float)(T_ - 1 - t) * invf;
  pe[idx] = f2bf((i < 256) ? sinf(a) : cosf(a));
}

// ---------------------------------------------------------------- fused fp32->bf16 (6 segments)
__global__ __launch_bounds__(256) void cvt6_kernel(
    const float* s0, ushort* d0, int n0,
    const float* s1, ushort* d1, int n1,
    const float* s2, ushort* d2, int n2,
    const float* s3, ushort* d3, int n3,
    const float* s4, ushort* d4, int n4,
    const float* s5, ushort* d5, int n5)
{
  const float* s; ushort* d; int n;
  switch (blockIdx.y) {
    case 0: s = s0; d = d0; n = n0; break;
    case 1: s = s1; d = d1; n = n1; break;
    case 2: s = s2; d = d2; n = n2; break;
    case 3: s = s3; d = d3; n = n3; break;
    case 4: s = s4; d = d4; n = n4; break;
    default: s = s5; d = d5; n = n5; break;
  }
  int i = blockIdx.x * 256 + threadIdx.x;
  if (i >= n) return;
  float4 v = ((const float4*)s)[i];
  ushort4 w = { f2bf(v.x), f2bf(v.y), f2bf(v.z), f2bf(v.w) };
  ((ushort4*)d)[i] = w;
}

// ---------------------------------------------------------------- clsw f32[64][512] -> bf16[128][512] zero-padded
__global__ __launch_bounds__(256) void clsw_cvt_kernel(const float* __restrict__ w,
                                                       ushort* __restrict__ wb) {
  int i = blockIdx.x * 256 + threadIdx.x;   // 16384 ushort4 groups = 128*512/4
  ushort4 o;
  if (i < 8192) {   // rows 0..63
    float4 v = ((const float4*)w)[i];
    o = ushort4{ f2bf(v.x), f2bf(v.y), f2bf(v.z), f2bf(v.w) };
  } else {
    o = ushort4{ 0, 0, 0, 0 };
  }
  ((ushort4*)wb)[i] = o;
}

// ---------------------------------------------------------------- x[B,C,T] -> xb[(t*2+b), C] bf16
__global__ __launch_bounds__(256) void xpose_kernel(const float* __restrict__ x,
                                                    ushort* __restrict__ xb) {
  __shared__ float s[32][33];
  int t0 = blockIdx.x * 32, k0 = blockIdx.y * 32, b = blockIdx.z;
  int tx = threadIdx.x & 31, ty = threadIdx.x >> 5;
#pragma unroll
  for (int l = 0; l < 4; ++l) {
    int k = k0 + ty + l * 8;
    s[ty + l * 8][tx] = x[((size_t)b * INCH + k) * T_ + t0 + tx];
  }
  __syncthreads();
#pragma unroll
  for (int l = 0; l < 4; ++l) {
    int t = t0 + ty + l * 8;
    xb[((size_t)(t * 2 + b)) * INCH + k0 + tx] = f2bf(s[tx][ty + l * 8]);
  }
}

// ---------------------------------------------------------------- bf16 MFMA GEMM (BK=64)
// OUTMODE: 0 = Cf only; 1 = Cb only; 2 = both; 3 = qkv-fused: Cb for
// col-blocks < 1024 (Q,K sections), V col-blocks (n0 >= 1024) transpose the
// C-tile through As/Bs LDS and write vtg[(b*8+n)*64+d][t] (Cf holds vtg).
template<int TM, int OUTMODE, bool RELU>
__global__ __launch_bounds__(256) void gemm_bf16(
    const ushort* __restrict__ A, const ushort* __restrict__ W,
    const float* __restrict__ bias, float* __restrict__ Cf, ushort* __restrict__ Cb,
    int M, int N, int K)
{
  __shared__ __attribute__((aligned(16))) ushort As[TM * 64];
  __shared__ __attribute__((aligned(16))) ushort Bs[128 * 64];
  const int NI = TM / 32;
  const int tid  = threadIdx.x;
  const int wave = tid >> 6, lane = tid & 63;
  const int quad = lane >> 4, lidx = lane & 15;
  const int m0 = blockIdx.y * TM, n0 = blockIdx.x * 128;
  const int r8 = lane >> 3;
  const int cs = ((lane & 7) ^ (r8 & 7)) * 8;

  float4v acc[NI * 4];
#pragma unroll
  for (int i = 0; i < NI * 4; ++i) acc[i] = (float4v){0.f, 0.f, 0.f, 0.f};

  const int wm = (wave >> 1) * (TM / 2), wn = (wave & 1) * 64;

  for (int k0 = 0; k0 < K; k0 += 64) {
    __syncthreads();
#pragma unroll
    for (int g = 0; g < TM / 32; ++g) {
      int r0 = wave * 8 + g * 32;
      gload16(A + (size_t)(m0 + r0 + r8) * K + k0 + cs, &As[r0 * 64]);
    }
#pragma unroll
    for (int g = 0; g < 4; ++g) {
      int r0 = wave * 8 + g * 32;
      gload16(W + (size_t)(n0 + r0 + r8) * K + k0 + cs, &Bs[r0 * 64]);
    }
    __syncthreads();

#pragma unroll
    for (int kb = 0; kb < 2; ++kb) {
      short8 af[NI], bf4[4];
      const int ch = (((kb * 4 + quad) ^ (lidx & 7)) * 8);
#pragma unroll
      for (int i = 0; i < NI; ++i)
        af[i] = *(const short8*)&As[(wm + i * 16 + lidx) * 64 + ch];
#pragma unroll
      for (int j = 0; j < 4; ++j)
        bf4[j] = *(const short8*)&Bs[(wn + j * 16 + lidx) * 64 + ch];
#pragma unroll
      for (int i = 0; i < NI; ++i)
#pragma unroll
        for (int j = 0; j < 4; ++j)
          acc[i * 4 + j] = __builtin_amdgcn_mfma_f32_16x16x32_bf16(af[i], bf4[j], acc[i * 4 + j], 0, 0, 0);
    }
  }

  float bj[4];
#pragma unroll
  for (int j = 0; j < 4; ++j) bj[j] = bias ? bias[n0 + wn + j * 16 + lidx] : 0.f;

  if (OUTMODE == 3 && n0 >= 1024) {
    // ---- fused V-transpose: C-tile (128x128, TM==128) -> vtg via LDS
    ushort* vt = (ushort*)Cf;   // vtg
    __syncthreads();   // all waves done reading As/Bs
#pragma unroll
    for (int i = 0; i < NI; ++i)
#pragma unroll
      for (int j = 0; j < 4; ++j)
#pragma unroll
        for (int reg = 0; reg < 4; ++reg) {
          int c2 = wn + j * 16 + lidx;            // local col 0..127
          int rl = wm + i * 16 + quad * 4 + reg;  // local row 0..127
          float v = acc[i * 4 + j][reg] + bj[j];
          ushort* buf = (c2 < 64) ? As : Bs;
          buf[(c2 & 63) * 128 + (rl ^ ((c2 & 7) << 4))] = f2bf(v);
        }
    __syncthreads();
    const int t0g = m0 >> 1;
    const int low = tid & 15, b2 = low & 1, tb = low >> 1;
#pragma unroll
    for (int s = 0; s < 8; ++s) {
      int dd = s * 16 + (tid >> 4);               // local col 0..127
      const ushort* buf = (dd < 64) ? As : Bs;
      ushort tmp[8];
#pragma unroll
      for (int q2 = 0; q2 < 8; ++q2) {
        int rl = (tb * 8 + q2) * 2 + b2;
        tmp[q2] = buf[(dd & 63) * 128 + (rl ^ ((dd & 7) << 4))];
      }
      int dg = n0 + dd - 1024;                    // global V col
      int n2h = dg >> 6, ddd = dg & 63;
      *(uint4*)&vt[((size_t)((b2 * 8 + n2h) * 64 + ddd)) * (size_t)T_ + t0g + tb * 8] = *(uint4*)tmp;
    }
  } else {
#pragma unroll
    for (int i = 0; i < NI; ++i) {
      int rbase = m0 + wm + i * 16 + quad * 4;
#pragma unroll
      for (int j = 0; j < 4; ++j) {
        int col = n0 + wn + j * 16 + lidx;
#pragma unroll
        for (int reg = 0; reg < 4; ++reg) {
          float v = acc[i * 4 + j][reg] + bj[j];
          if (RELU) v = fmaxf(v, 0.f);
          size_t off = (size_t)(rbase + reg) * N + col;
          if (OUTMODE == 0 || OUTMODE == 2) Cf[off] = v;
          if (OUTMODE != 0) Cb[off] = f2bf(v);
        }
      }
    }
  }
}

// ---------------------------------------------------------------- MFMA flash rel-attn (swapped, split-K)
// Grid 1536 blocks; flat id F remapped XCD-exact-fit (XCD = F%8): each XCD's
// blocks share one bn working set -> K/V/rk L2-resident. Block: 64 q-rows of
// one (b,n); wave owns q-row strip. AC swapped: S^T = mfma(K, Q), S lane-local
// per q-row. Re is a 128-row RING with offset roff in {0,64}: the window
// slides 64 rows/iter, so only 64 new rows are DMA'd per iter. rel_shift
// gather from Gbt with uniform sel fast paths; no-max base-2 softmax in regs
// (raw v_exp_f32); P packed via v_cvt_pk_bf16_f32 + permlane{32,16}_swap;
// PV before B2. O/li chunk partials to disjoint buffers (plain stores).
#define GT 68

__device__ inline short8 bfrag(const char* base, int lidx, int quad, int kb) {
  return *(const short8*)(base + lidx * 128 + ((((kb << 2) + quad) ^ (lidx & 7)) << 4));
}

__global__ __launch_bounds__(256, 3) void attn_mfma_kernel(
    const ushort* __restrict__ heads, const ushort* __restrict__ rk,
    const ushort* __restrict__ vtg,
    const float* __restrict__ rwb, const float* __restrict__ rrb,
    float* __restrict__ O0, float* __restrict__ O1, float* __restrict__ O2,
    float* __restrict__ Lp)
{
  __shared__ __attribute__((aligned(16))) ushort Ks[64 * 64];    // swizzled [key][d]
  __shared__ __attribute__((aligned(16))) ushort Vt[64 * 64];    // swizzled [d][key]
  __shared__ __attribute__((aligned(16))) ushort Re[128 * 64];   // swizzled [w][d], ring
  __shared__ __attribute__((aligned(16))) ushort Gbt[128 * GT];  // [w][grow]

  const int tid  = threadIdx.x;
  // ---- XCD-exact-fit remap (assumes XCD = flat%8 round-robin dispatch).
  const int F = blockIdx.x + ((blockIdx.y + (blockIdx.z << 4)) << 5);  // x + 32y + 512z
  const int g  = F & 7;
  const int k  = F >> 3;          // 0..191
  const int r  = k / 96;          // round 0/1
  const int kk = k - r * 96;      // 0..95
  const int bnl = r * 8 + g;      // logical bn
  const int i0   = (kk & 31) * 64;
  const int chunk = kk >> 5;      // 0..2
  const int b    = bnl & 1;
  const int n    = bnl >> 1;
  const int jt0 = (chunk == 0) ? 0  : (chunk == 1 ? 11 : 22);
  const int jt1 = (chunk == 0) ? 11 : (chunk == 1 ? 22 : 32);
  const int wave = tid >> 6;
  const int lane = tid & 63;
  const int quad = lane >> 4;
  const int lidx = lane & 15;
  const int r8   = lane >> 3;
  const int cs8  = ((lane & 7) ^ (r8 & 7)) * 8;
  const int bn64 = (b * 8 + n) * 64;
  const int rloc = wave * 16 + lidx;   // this thread's q-row within block

  // ---- Q fragments in registers.
  short8 qw[2], qr4[4][2], q4[2];
  {
    auto qfrag = [&](int row, int kb, const float* bias) -> short8 {
      short8 q;
      if (row < T_) q = *(const short8*)&heads[(size_t)(row * 2 + b) * 1536 + n * 64 + kb * 32 + quad * 8];
      else { for (int t = 0; t < 8; ++t) ((ushort*)&q)[t] = 0; }
      short8 o;
#pragma unroll
      for (int t = 0; t < 8; ++t) {
        float f = (bf2f((ushort)((ushort*)&q)[t]) + bias[n * 64 + kb * 32 + quad * 8 + t]) * QSCALE;
        ((ushort*)&o)[t] = f2bf(f);
      }
      return o;
    };
    qw[0] = qfrag(i0 + rloc, 0, rwb);
    qw[1] = qfrag(i0 + rloc, 1, rwb);
#pragma unroll
    for (int rt = 0; rt < 4; ++rt) {
      int row = i0 + rt * 16 + lidx;
      qr4[rt][0] = qfrag(row, 0, rrb); qr4[rt][1] = qfrag(row, 1, rrb);
    }
    int row4 = i0 + 64 + lidx;
    q4[0] = qfrag(row4, 0, rrb); q4[1] = qfrag(row4, 1, rrb);
  }

  // loop-invariant gather bases: per ktile t, addr of Gbt[w(c0)][rloc]
  int a0[4];
#pragma unroll
  for (int t = 0; t < 4; ++t)
    a0[t] = (t * 16 + quad * 4 + 63 - rloc) * GT + rloc;

  float4v oacc[4];
  float4v liacc = (float4v){0.f, 0.f, 0.f, 0.f};
#pragma unroll
  for (int dt = 0; dt < 4; ++dt) oacc[dt] = (float4v){0.f, 0.f, 0.f, 0.f};
  short8 ones8;
#pragma unroll
  for (int t = 0; t < 8; ++t) ((ushort*)&ones8)[t] = 0x3F80;   // bf16 1.0

  auto stageK = [&](int jt) {
    int j0 = jt * 64;
#pragma unroll
    for (int half = 0; half < 2; ++half) {
      int r0 = 8 * wave + 32 * half;
      gload16(heads + (size_t)((j0 + r0 + r8) * 2 + b) * 1536 + 512 + n * 64 + cs8, &Ks[r0 * 64]);
    }
  };
  auto stageReFull = [&](int jt) {   // all 128 window rows, phys = logical (roff=0)
    int qmin = jt * 64 + 1984 - i0;
#pragma unroll
    for (int q4i = 0; q4i < 4; ++q4i) {
      int r0 = 8 * wave + 32 * q4i;
      int qh = qmin + r0 + r8;
      int p  = (qh > T_) ? (qh - T_ - 1) : ((qh == T_) ? 0 : qh);
      gload16(rk + (size_t)p * 2048 + n * 64 + cs8, &Re[r0 * 64]);
    }
  };
  auto stageReNew = [&](int jt, int roff) {   // 64 new rows for window jt+1
    int qmin = jt * 64 + 1984 - i0;           // w = qmin+128+u -> phys u+roff
#pragma unroll
    for (int half = 0; half < 2; ++half) {
      int u0 = 8 * wave + 32 * half;
      int qh = qmin + 128 + u0 + r8;
      int p  = (qh > T_) ? (qh - T_ - 1) : ((qh == T_) ? 0 : qh);
      gload16(rk + (size_t)p * 2048 + n * 64 + cs8, &Re[(u0 + roff) * 64]);
    }
  };
  auto stageV = [&](int jt) {
    int j0 = jt * 64;
#pragma unroll
    for (int half = 0; half < 2; ++half) {
      int r0 = 8 * wave + 32 * half;
      gload16(vtg + (size_t)(bn64 + r0 + r8) * (size_t)T_ + j0 + cs8, &Vt[r0 * 64]);
    }
  };

  stageK(jt0);
  stageReFull(jt0);
  stageV(jt0);
  __syncthreads();
  {   // initial Rext[T]=0 fixup (full window, phys = logical)
    int Tidx = T_ - (jt0 * 64 + 1984 - i0);
    if (Tidx >= 0 && Tidx < 128) {
      if (tid < 32) ((uint*)Re)[Tidx * 32 + tid] = 0u;
      __syncthreads();
    }
  }

  int roff = 0;   // ring offset, toggles 0<->64 per iteration

  for (int jt = jt0; jt < jt1; ++jt) {
    const int qmin = jt * 64 + 1984 - i0;
    const int wth  = T_ - qmin;   // sel = (w > wth)

    // ---- AC swapped: sv[t][reg] = S[key t*16+quad*4+reg][row lidx(=rloc)]
    float4v sv[4];
#pragma unroll
    for (int t = 0; t < 4; ++t) {
      const char* KsT = (const char*)Ks + t * 2048;
      short8 kf0 = bfrag(KsT, lidx, quad, 0);
      short8 kf1 = bfrag(KsT, lidx, quad, 1);
      float4v c = {0.f, 0.f, 0.f, 0.f};
      c = __builtin_amdgcn_mfma_f32_16x16x32_bf16(kf0, qw[0], c, 0, 0, 0);
      c = __builtin_amdgcn_mfma_f32_16x16x32_bf16(kf1, qw[1], c, 0, 0, 0);
      sv[t] = c;
    }

    // ---- G: strips {wave, wave+4}; C: col->w, row->grow; aligned uint2 stores
#pragma unroll
    for (int si = 0; si < 2; ++si) {
      const int ws = wave + si * 4;
      const int w0 = ws * 16;
      const char* ReW = (const char*)Re + (size_t)(((w0 + roff) & 127) * 128);
      short8 rb0 = bfrag(ReW, lidx, quad, 0);
      short8 rb1 = bfrag(ReW, lidx, quad, 1);
#pragma unroll
      for (int rt = 0; rt < 4; ++rt) {
        bool need = si == 0 ? (rt >= 3 - wave) : (rt <= 3 - wave);
        if (need) {
          float4v g2 = {0.f, 0.f, 0.f, 0.f};
          g2 = __builtin_amdgcn_mfma_f32_16x16x32_bf16(qr4[rt][0], rb0, g2, 0, 0, 0);
          g2 = __builtin_amdgcn_mfma_f32_16x16x32_bf16(qr4[rt][1], rb1, g2, 0, 0, 0);
          uint2 st; st.x = pkbf(g2[0], g2[1]); st.y = pkbf(g2[2], g2[3]);
          *(uint2*)&Gbt[(w0 + lidx) * GT + rt * 16 + quad * 4] = st;
        }
      }
      if (si == 0 && wth < 63) {   // grow=64 row (for sel at r=63), strips w<64
        float4v g2 = {0.f, 0.f, 0.f, 0.f};
        g2 = __builtin_amdgcn_mfma_f32_16x16x32_bf16(q4[0], rb0, g2, 0, 0, 0);
        g2 = __builtin_amdgcn_mfma_f32_16x16x32_bf16(q4[1], rb1, g2, 0, 0, 0);
        if (quad == 0) Gbt[(w0 + lidx) * GT + 64] = f2bf(g2[0]);
      }
    }
    __syncthreads();   // B1: Gbt ready; Ks/Re consumed; Vt(jt) DMA drained

    if (jt + 1 < jt1) {
      stageK(jt + 1);            // DMA overlaps gather+pack+PV; drains at B2
      stageReNew(jt, roff);      // 64 new ring rows into freed half
    }

    // ---- gather BD + no-max base-2 softmax, in registers (raw v_exp_f32)
    // sel = (c > cth) is block-uniform-classifiable: no-sel iff wth>=126,
    // all-sel iff wth<0; mixed hits <=2 iterations per block.
    if (wth >= 126) {
#pragma unroll
      for (int t = 0; t < 4; ++t)
#pragma unroll
        for (int r2 = 0; r2 < 4; ++r2)
          sv[t][r2] = __builtin_amdgcn_exp2f(sv[t][r2] + bf2f(Gbt[a0[t] + r2 * GT]));
    } else if (wth < 0) {
#pragma unroll
      for (int t = 0; t < 4; ++t)
#pragma unroll
        for (int r2 = 0; r2 < 4; ++r2)
          sv[t][r2] = __builtin_amdgcn_exp2f(sv[t][r2] + bf2f(Gbt[a0[t] + r2 * GT + 1]));
    } else {
      const int cth = wth + rloc - 63;   // sel = (c > cth)
#pragma unroll
      for (int t = 0; t < 4; ++t) {
        const int c0 = t * 16 + quad * 4;
#pragma unroll
        for (int r2 = 0; r2 < 4; ++r2) {
          int ga = a0[t] + r2 * GT + ((c0 + r2 > cth) ? 1 : 0);
          sv[t][r2] = __builtin_amdgcn_exp2f(sv[t][r2] + bf2f(Gbt[ga]));
        }
      }
    }

    // ---- V fragments (B-operand: V[key][d], d = dt*16+lidx)
    short8 vb[4][2];
#pragma unroll
    for (int dt = 0; dt < 4; ++dt) {
      const char* VtT = (const char*)Vt + dt * 2048;
      vb[dt][0] = bfrag(VtT, lidx, quad, 0);
      vb[dt][1] = bfrag(VtT, lidx, quad, 1);
    }

    // ---- pack P to bf16 + in-register quad redistribution -> PV A-frags
    // af[kb] elem j = P[row=lidx][key kb*32+quad*8+j]
    short8 af[2];
#pragma unroll
    for (int kb = 0; kb < 2; ++kb) {
      uint mm[4];
#pragma unroll
      for (int i = 0; i < 2; ++i) {
        uint e, o;
        asm("v_cvt_pk_bf16_f32 %0, %1, %2" : "=v"(e) : "v"(sv[2 * kb][2 * i]),     "v"(sv[2 * kb][2 * i + 1]));
        asm("v_cvt_pk_bf16_f32 %0, %1, %2" : "=v"(o) : "v"(sv[2 * kb + 1][2 * i]), "v"(sv[2 * kb + 1][2 * i + 1]));
        asm("v_permlane32_swap_b32 %0, %1" : "+v"(e), "+v"(o));
        asm("v_permlane16_swap_b32 %0, %1" : "+v"(e), "+v"(o));
        mm[i] = e; mm[2 + i] = o;
      }
      union { uint u[4]; short8 s; } cv;
      cv.u[0] = mm[0]; cv.u[1] = mm[1]; cv.u[2] = mm[2]; cv.u[3] = mm[3];
      af[kb] = cv.s;
    }

    // ---- PV + li (pure registers, no LDS): before B2 to extend DMA shadow
#pragma unroll
    for (int dt = 0; dt < 4; ++dt) {
      oacc[dt] = __builtin_amdgcn_mfma_f32_16x16x32_bf16(af[0], vb[dt][0], oacc[dt], 0, 0, 0);
      oacc[dt] = __builtin_amdgcn_mfma_f32_16x16x32_bf16(af[1], vb[dt][1], oacc[dt], 0, 0, 0);
    }
    liacc = __builtin_amdgcn_mfma_f32_16x16x32_bf16(af[0], ones8, liacc, 0, 0, 0);
    liacc = __builtin_amdgcn_mfma_f32_16x16x32_bf16(af[1], ones8, liacc, 0, 0, 0);

    __syncthreads();   // B2: Gbt/Vt consumed; K/ReNew(jt+1) DMA drained

    if (jt + 1 < jt1) {
      stageV(jt + 1);   // DMA overlaps next AC/G; drains at next B1
      roff ^= 64;       // ring advances: next window's logical 0 at new offset
      {   // Rext[T]=0 fixup, only if T is among the newly staged 64 rows
        int Tn = T_ - ((jt + 1) * 64 + 1984 - i0);
        if (Tn >= 64 && Tn < 128) {
          int phys = (Tn + roff) & 127;
          if (tid < 32) ((uint*)Re)[phys * 32 + tid] = 0u;
          __syncthreads();   // orders the write before next iter's G reads
        }
      }
    }
  }

  // ---- epilogue: plain stores to this chunk's disjoint partial buffer
  float* __restrict__ Oc = (chunk == 0) ? O0 : (chunk == 1 ? O1 : O2);
  float* __restrict__ Lc = Lp + chunk * (16 * T_);
  const int rowg0 = (b * 8 + n) * T_ + i0 + wave * 16 + quad * 4;
#pragma unroll
  for (int reg = 0; reg < 4; ++reg) {
    int rowg = rowg0 + reg;
#pragma unroll
    for (int dt = 0; dt < 4; ++dt)
      Oc[(size_t)rowg * 64 + dt * 16 + lidx] = oacc[dt][reg];
    if (lidx == 0) Lc[rowg] = liacc[reg];
  }
}

// ---------------------------------------------------------------- sum partials, normalize -> avec bf16
__global__ __launch_bounds__(256) void attn_norm_kernel(
    const float* __restrict__ O0, const float* __restrict__ O1,
    const float* __restrict__ O2, const float* __restrict__ Lp,
    ushort* __restrict__ avec)
{
  int idx = blockIdx.x * 256 + threadIdx.x;   // over [bn][row][d4], 16*2048*16
  int d4  = idx & 15;
  int row = (idx >> 4) & 2047;
  int bn  = idx >> 15;
  float4 v0 = ((const float4*)O0)[idx];
  float4 v1 = ((const float4*)O1)[idx];
  float4 v2 = ((const float4*)O2)[idx];
  int rg = (bn << 11) + row;
  float li = Lp[rg] + Lp[rg + 16 * T_] + Lp[rg + 32 * T_];
  float inv = 1.0f / li;
  int b = bn >> 3, n = bn & 7;
  ushort4 w = { f2bf((v0.x + v1.x + v2.x) * inv), f2bf((v0.y + v1.y + v2.y) * inv),
                f2bf((v0.z + v1.z + v2.z) * inv), f2bf((v0.w + v1.w + v2.w) * inv) };
  *(ushort4*)&avec[(size_t)(row * 2 + b) * DM + n * 64 + d4 * 4] = w;
}

// ---------------------------------------------------------------- LN(residual), dual out
__global__ __launch_bounds__(256) void ln_res_kernel(
    float* __restrict__ h, ushort* __restrict__ hb, const float* __restrict__ delta,
    const float* __restrict__ s, const float* __restrict__ bb)
{
  const int m = blockIdx.x;
  const int tid = threadIdx.x;
  float* hp = h + (size_t)m * DM;
  ushort* hbp = hb + (size_t)m * DM;
  const float* dp = delta + (size_t)m * DM;
  float x0 = hp[tid] + dp[tid];
  float x1 = hp[tid + 256] + dp[tid + 256];
  float sum = x0 + x1, sq = x0 * x0 + x1 * x1;
#pragma unroll
  for (int o = 32; o > 0; o >>= 1) { sum += __shfl_down(sum, o); sq += __shfl_down(sq, o); }
  __shared__ float part[8];
  int wv = tid >> 6;
  if ((tid & 63) == 0) { part[wv * 2] = sum; part[wv * 2 + 1] = sq; }
  __syncthreads();
  float ts = part[0] + part[2] + part[4] + part[6];
  float tq = part[1] + part[3] + part[5] + part[7];
  float mu = ts * (1.f / DM);
  float var = tq * (1.f / DM) - mu * mu;
  float rs = rsqrtf(var + 1e-5f);
  float y0 = (x0 - mu) * rs * s[tid]       + bb[tid];
  float y1 = (x1 - mu) * rs * s[tid + 256] + bb[tid + 256];
  hp[tid] = y0;       hbp[tid] = f2bf(y0);
  hp[tid + 256] = y1; hbp[tid + 256] = f2bf(y1);
}

// ---------------------------------------------------------------- classifier reorder (+bias)
__global__ __launch_bounds__(256) void reorder_kernel(const float* __restrict__ ct,
                                                      const float* __restrict__ cb,
                                                      float* __restrict__ out) {
  int idx = blockIdx.x * 256 + threadIdx.x;
  if (idx >= B_ * NCLS * T_) return;
  int t  = idx & (T_ - 1);
  int nc = (idx >> 11) & 63;
  int bb = idx >> 17;
  out[idx] = ct[(size_t)(t * B_ + bb) * 128 + nc] + cb[nc];
}

// ---------------------------------------------------------------- launch
extern "C" void kernel_launch(void* const* d_in, const int* in_sizes, int n_in,
                              void* d_out, int out_size, void* d_ws, size_t ws_size,
                              hipStream_t stream)
{
  const float* x     = (const float*)d_in[0];
  const float* emb_w = (const float*)d_in[1];
  const float* emb_b = (const float*)d_in[2];
  const float* rwb   = (const float*)d_in[3];
  const float* rrb   = (const float*)d_in[4];
  const float* qkv_w = (const float*)d_in[5];
  const float* qkv_b = (const float*)d_in[6];
  const float* rproj = (const float*)d_in[7];
  const float* o_w   = (const float*)d_in[8];
  const float* ln1s  = (const float*)d_in[9];
  const float* ln1b  = (const float*)d_in[10];
  const float* ff1w  = (const float*)d_in[11];
  const float* ff1b  = (const float*)d_in[12];
  const float* ff2w  = (const float*)d_in[13];
  const float* ff2b  = (const float*)d_in[14];
  const float* ln2s  = (const float*)d_in[15];
  const float* ln2b  = (const float*)d_in[16];
  const float* clsw  = (const float*)d_in[17];
  const float* clsb  = (const float*)d_in[18];
  float* out = (float*)d_out;

  char* p = (char*)d_ws;
  float*  h       = (float*)p;   p += (size_t)MT * DM * 4;
  float*  tmpf    = (float*)p;   p += (size_t)MT * DM * 4;
  ushort* hb      = (ushort*)p;  p += (size_t)MT * DM * 2;
  ushort* headsb  = (ushort*)p;  p += (size_t)MT * 1536 * 2;
  ushort* peb     = (ushort*)p;  p += (size_t)T_ * DM * 2;
  ushort* rk_all  = (ushort*)p;  p += (size_t)T_ * 2048 * 2;
  ushort* avecb   = (ushort*)p;  p += (size_t)MT * DM * 2;
  ushort* xfb     = (ushort*)p;  p += (size_t)MT * INCH * 2;
  ushort* emb_wb  = (ushort*)p;  p += (size_t)DM * INCH * 2;
  ushort* qkv_wb  = (ushort*)p;  p += (size_t)4 * 1536 * DM * 2;
  ushort* rproj_wb= (ushort*)p;  p += (size_t)4 * DM * DM * 2;
  ushort* o_wb    = (ushort*)p;  p += (size_t)4 * DM * DM * 2;
  ushort* ff1_wb  = (ushort*)p;  p += (size_t)4 * DI * DM * 2;
  ushort* ff2_wb  = (ushort*)p;  p += (size_t)4 * DM * DI * 2;
  float*  P2      = (float*)p;   p += (size_t)MT * DM * 4;   // chunk-2 O partial
  float*  Lp      = (float*)p;   p += (size_t)3 * 16 * T_ * 4;
  ushort* cls_wb  = (ushort*)p;  p += (size_t)128 * DM * 2;  // zero-padded bf16 clsw
  ushort* vtg     = xfb;   // region reused; live only qkv->attn
  // chunk-0 partial = tmpf (free during attn); chunk-1 partial = xfb tail
  // (xfb is 16 MB; vtg uses only the first 4 MB; ff1 rewrites xfb later).
  float*  P0      = tmpf;
  float*  P1      = (float*)(xfb + (size_t)16 * 64 * T_);   // xfb + 4 MB

  cvt6_kernel<<<dim3(4096, 6), 256, 0, stream>>>(
      emb_w, emb_wb, DM * INCH / 4,
      qkv_w, qkv_wb, 4 * 1536 * DM / 4,
      rproj, rproj_wb, 4 * DM * DM / 4,
      o_w,   o_wb,   4 * DM * DM / 4,
      ff1w,  ff1_wb, 4 * DI * DM / 4,
      ff2w,  ff2_wb, 4 * DM * DI / 4);
  clsw_cvt_kernel<<<64, 256, 0, stream>>>(clsw, cls_wb);
  pos_kernel<<<(T_ * DM) / 256, 256, 0, stream>>>(peb);
  xpose_kernel<<<dim3(T_ / 32, INCH / 32, B_), 256, 0, stream>>>(x, xfb);

  gemm_bf16<64, 2, false><<<dim3(DM / 128, MT / 64), 256, 0, stream>>>(
      xfb, emb_wb, emb_b, h, hb, MT, DM, INCH);
  gemm_bf16<128, 1, false><<<dim3(2048 / 128, T_ / 128), 256, 0, stream>>>(
      peb, rproj_wb, nullptr, nullptr, rk_all, T_, 2048, DM);

  for (int l = 0; l < 4; ++l) {
    // qkv GEMM with fused V-transpose: Q,K -> headsb; V col-blocks -> vtg
    gemm_bf16<128, 3, false><<<dim3(1536 / 128, MT / 128), 256, 0, stream>>>(
        hb, qkv_wb + (size_t)l * 1536 * DM, qkv_b + l * 1536, (float*)vtg, headsb, MT, 1536, DM);
    attn_mfma_kernel<<<dim3(T_ / 64, B_ * NH, 3), 256, 0, stream>>>(
        headsb, rk_all + (size_t)l * 512, vtg, rwb, rrb, P0, P1, P2, Lp);
    attn_norm_kernel<<<(16 * T_ * 16) / 256, 256, 0, stream>>>(P0, P1, P2, Lp, avecb);
    gemm_bf16<32, 0, false><<<dim3(DM / 128, MT / 32), 256, 0, stream>>>(
        avecb, o_wb + (size_t)l * DM * DM, nullptr, tmpf, nullptr, MT, DM, DM);
    ln_res_kernel<<<MT, 256, 0, stream>>>(h, hb, tmpf, ln1s + l * DM, ln1b + l * DM);
    gemm_bf16<128, 1, true><<<dim3(DI / 128, MT / 128), 256, 0, stream>>>(
        hb, ff1_wb + (size_t)l * DI * DM, ff1b + l * DI, nullptr, xfb, MT, DI, DM);
    gemm_bf16<32, 0, false><<<dim3(DM / 128, MT / 32), 256, 0, stream>>>(
        xfb, ff2_wb + (size_t)l * DM * DI, ff2b + l * DM, tmpf, nullptr, MT, DM, DI);
    ln_res_kernel<<<MT, 256, 0, stream>>>(h, hb, tmpf, ln2s + l * DM, ln2b + l * DM);
  }

  // classifier: bf16 MFMA, N padded to 128 (rows 64.. are zero); bias in reorder
  gemm_bf16<32, 0, false><<<dim3(1, MT / 32), 256, 0, stream>>>(
      hb, cls_wb, nullptr, tmpf, nullptr, MT, 128, DM);
  reorder_kernel<<<(B_ * NCLS * T_) / 256, 256, 0, stream>>>(tmpf, clsb, out);
}